// Round 7
// baseline (659.501 us; speedup 1.0000x reference)
//
#include <hip/hip_runtime.h>
#include <hip/hip_bf16.h>
#include <math.h>

#define DIMSZ 1024
#define NHEAD 16
#define HDIM 64
#define FFDIM 4096
#define SEQ 2048
#define NBATCH 2

typedef unsigned short ushortt;
typedef __attribute__((ext_vector_type(8))) short frag8;   // 8 bf16 (4 VGPR)
typedef __attribute__((ext_vector_type(4))) float f32x4;   // MFMA acc

// bf16 (stored as ushort) <-> fp32
__device__ __forceinline__ float u2f(ushortt u) {
  return __uint_as_float(((unsigned)u) << 16);
}
__device__ __forceinline__ ushortt f2bu(float f) {  // RNE
  unsigned x = __float_as_uint(f);
  return (ushortt)((x + 0x7FFFu + ((x >> 16) & 1u)) >> 16);
}

// ---------------------------------------------------------------------------
// fp32 -> bf16 cast, 4 elems/thread, n % 4 == 0
// ---------------------------------------------------------------------------
__global__ __launch_bounds__(256) void cast_f2b(
    const float* __restrict__ src, ushortt* __restrict__ dst, int n) {
  int i = (blockIdx.x * 256 + threadIdx.x) * 4;
  if (i >= n) return;
  float4 f = *(const float4*)(src + i);
  ushort4 u;
  u.x = f2bu(f.x); u.y = f2bu(f.y); u.z = f2bu(f.z); u.w = f2bu(f.w);
  *(ushort4*)(dst + i) = u;
}

// ---------------------------------------------------------------------------
// zero fp32 buffer (pre-pass for atomic-accumulate GEMMs), n % 4 == 0
// ---------------------------------------------------------------------------
__global__ __launch_bounds__(256) void zero_f32(float* __restrict__ p, int n) {
  int i = (blockIdx.x * 256 + threadIdx.x) * 4;
  if (i < n) *(float4*)(p + i) = make_float4(0.f, 0.f, 0.f, 0.f);
}

// ---------------------------------------------------------------------------
// MFMA GEMM, double-buffered (STAGE(t+1) before compute(t), 1 barrier/K-step).
// 1D grid, XCD-grouped decode (id%8 = XCD; 4 y-panels per XCD -> A stays in
// that XCD's L2). SK=2 adds split-K: 2 blocks per output tile handle disjoint
// K-halves (KB each), doubling blocks/CU on small grids; both kz-halves of a
// tile group stay on the same XCD.
// EPI: 0 fp32 store | 1 bf16 store | 2 fp32 unsafeAtomicAdd (needs zeroed C)
// ---------------------------------------------------------------------------
template <int EPI, int SK>
__global__ __launch_bounds__(256) void gemm_mfma(
    const ushortt* __restrict__ A, const ushortt* __restrict__ W,
    void* __restrict__ Cv, int M, int N, int K, int KB) {
  __shared__ __align__(16) short As[2][128 * 32];
  __shared__ __align__(16) short Bs[2][128 * 32];
  const int tid = threadIdx.x;
  const int wave = tid >> 6;
  const int lane = tid & 63;
  int xcd = blockIdx.x & 7, r = blockIdx.x >> 3, kz = 0;
  if (SK == 2) { kz = r & 1; r >>= 1; }
  const int bm = (xcd * 4 + (r & 3)) * 128;
  const int bn = (r >> 2) * 128;
  const int ko0 = kz * KB;
  const int wm = (wave >> 1) * 64;
  const int wn = (wave & 1) * 64;

  f32x4 acc[4][4] = {};

  const int sr = lane >> 2;
  const int sc = (lane & 3) * 8;
  const ushortt* pa0 = A + (size_t)(bm + wave * 16 + sr) * K + ko0 + sc;
  const ushortt* pa1 = pa0 + (size_t)64 * K;
  const ushortt* pb0 = W + (size_t)(bn + wave * 16 + sr) * K + ko0 + sc;
  const ushortt* pb1 = pb0 + (size_t)64 * K;
  const int lo0 = (wave * 16) * 32;
  const int lo1 = (64 + wave * 16) * 32;

  const int fr = lane & 15;
  const int fq = (lane >> 4) * 8;
  const int nt = KB >> 5;

  auto stage = [&](int t, int buf) {
    const int ko = t * 32;
    short* ab = &As[0][0] + buf * 4096;
    short* bb = &Bs[0][0] + buf * 4096;
    __builtin_amdgcn_global_load_lds(
        (const __attribute__((address_space(1))) void*)(pa0 + ko),
        (__attribute__((address_space(3))) void*)(ab + lo0), 16, 0, 0);
    __builtin_amdgcn_global_load_lds(
        (const __attribute__((address_space(1))) void*)(pa1 + ko),
        (__attribute__((address_space(3))) void*)(ab + lo1), 16, 0, 0);
    __builtin_amdgcn_global_load_lds(
        (const __attribute__((address_space(1))) void*)(pb0 + ko),
        (__attribute__((address_space(3))) void*)(bb + lo0), 16, 0, 0);
    __builtin_amdgcn_global_load_lds(
        (const __attribute__((address_space(1))) void*)(pb1 + ko),
        (__attribute__((address_space(3))) void*)(bb + lo1), 16, 0, 0);
  };

  stage(0, 0);
  __syncthreads();

  for (int t = 0; t < nt; ++t) {
    if (t + 1 < nt) stage(t + 1, (t + 1) & 1);
    const short* as = &As[0][0] + (t & 1) * 4096;
    const short* bs = &Bs[0][0] + (t & 1) * 4096;

    frag8 af[4], bf[4];
#pragma unroll
    for (int mi = 0; mi < 4; ++mi)
      af[mi] = *(const frag8*)&as[(wm + mi * 16 + fr) * 32 + fq];
#pragma unroll
    for (int ni = 0; ni < 4; ++ni)
      bf[ni] = *(const frag8*)&bs[(wn + ni * 16 + fr) * 32 + fq];
#pragma unroll
    for (int mi = 0; mi < 4; ++mi)
#pragma unroll
      for (int ni = 0; ni < 4; ++ni)
        acc[mi][ni] = __builtin_amdgcn_mfma_f32_16x16x32_bf16(
            af[mi], bf[ni], acc[mi][ni], 0, 0, 0);
    __syncthreads();
  }

  const int er = (lane >> 4) * 4;
  const int ec = lane & 15;
#pragma unroll
  for (int mi = 0; mi < 4; ++mi)
#pragma unroll
    for (int ni = 0; ni < 4; ++ni)
#pragma unroll
      for (int r2 = 0; r2 < 4; ++r2) {
        int m = bm + wm + mi * 16 + er + r2;
        int n = bn + wn + ni * 16 + ec;
        size_t o = (size_t)m * N + n;
        float v = acc[mi][ni][r2];
        if (EPI == 0) {
          ((float*)Cv)[o] = v;
        } else if (EPI == 1) {
          ((ushortt*)Cv)[o] = f2bu(v);
        } else {
          unsafeAtomicAdd((float*)Cv + o, v);
        }
      }
}

// ---------------------------------------------------------------------------
// Fused gate+lin GEMM with on-the-fly fp32->bf16 B staging (no pre-cast).
// One A tile (gload_lds) feeds TWO reg-staged B tiles; 32 MFMA/K-step.
// B loads for t+1 issued before compute(t), ds_write after (T14).
// Epilogue: out = sigmoid(g+gbias)*(l+lbias) -> bf16.
// Wg/Wl point at the fp32 chunk rows [c*2048 .. +2048) of [4096][1024].
// ---------------------------------------------------------------------------
__global__ __launch_bounds__(256) void gemm_gatelin(
    const ushortt* __restrict__ A, const float* __restrict__ Wg,
    const float* __restrict__ Wl, ushortt* __restrict__ Cv,
    const float* __restrict__ gbias, const float* __restrict__ lbias,
    int M, int N, int K) {
  __shared__ __align__(16) short As[2][128 * 32];
  __shared__ __align__(16) short Gs[2][128 * 32];
  __shared__ __align__(16) short Ls[2][128 * 32];
  const int tid = threadIdx.x;
  const int wave = tid >> 6;
  const int lane = tid & 63;
  int xcd = blockIdx.x & 7, r = blockIdx.x >> 3;
  const int bm = (xcd * 4 + (r & 3)) * 128;
  const int bn = (r >> 2) * 128;
  const int wm = (wave >> 1) * 64;
  const int wn = (wave & 1) * 64;

  f32x4 accg[4][4] = {};
  f32x4 accl[4][4] = {};

  const int sr = lane >> 2;
  const int sc = (lane & 3) * 8;
  const ushortt* pa0 = A + (size_t)(bm + wave * 16 + sr) * K + sc;
  const ushortt* pa1 = pa0 + (size_t)64 * K;
  const int lo0 = (wave * 16) * 32;
  const int lo1 = (64 + wave * 16) * 32;

  // B reg-stage: thread -> row br (and br+64), k-part kc of the 32-k step
  const int br = tid >> 2;
  const int kc = (tid & 3) * 8;
  const float* pg = Wg + (size_t)(bn + br) * DIMSZ + kc;
  const float* pl = Wl + (size_t)(bn + br) * DIMSZ + kc;

  const int fr = lane & 15;
  const int fq = (lane >> 4) * 8;
  const int nt = K >> 5;

  float4 g0, g1, g2, g3, l0, l1, l2, l3;
  auto bload = [&](int t) {
    const float* p = pg + t * 32;
    g0 = *(const float4*)p; g1 = *(const float4*)(p + 4);
    g2 = *(const float4*)(p + 64 * DIMSZ); g3 = *(const float4*)(p + 64 * DIMSZ + 4);
    const float* q = pl + t * 32;
    l0 = *(const float4*)q; l1 = *(const float4*)(q + 4);
    l2 = *(const float4*)(q + 64 * DIMSZ); l3 = *(const float4*)(q + 64 * DIMSZ + 4);
  };
  auto pk = [&](float4 a, float4 b) {
    frag8 v;
    v[0] = (short)f2bu(a.x); v[1] = (short)f2bu(a.y);
    v[2] = (short)f2bu(a.z); v[3] = (short)f2bu(a.w);
    v[4] = (short)f2bu(b.x); v[5] = (short)f2bu(b.y);
    v[6] = (short)f2bu(b.z); v[7] = (short)f2bu(b.w);
    return v;
  };
  auto bwrite = [&](int buf) {
    *(frag8*)&Gs[buf][tid * 8] = pk(g0, g1);
    *(frag8*)&Gs[buf][2048 + tid * 8] = pk(g2, g3);
    *(frag8*)&Ls[buf][tid * 8] = pk(l0, l1);
    *(frag8*)&Ls[buf][2048 + tid * 8] = pk(l2, l3);
  };
  auto astage = [&](int t, int buf) {
    const int ko = t * 32;
    short* ab = &As[0][0] + buf * 4096;
    __builtin_amdgcn_global_load_lds(
        (const __attribute__((address_space(1))) void*)(pa0 + ko),
        (__attribute__((address_space(3))) void*)(ab + lo0), 16, 0, 0);
    __builtin_amdgcn_global_load_lds(
        (const __attribute__((address_space(1))) void*)(pa1 + ko),
        (__attribute__((address_space(3))) void*)(ab + lo1), 16, 0, 0);
  };

  astage(0, 0);
  bload(0);
  bwrite(0);
  __syncthreads();

  for (int t = 0; t < nt; ++t) {
    if (t + 1 < nt) {
      astage(t + 1, (t + 1) & 1);
      bload(t + 1);
    }
    const short* as = &As[0][0] + (t & 1) * 4096;
    const short* gs = &Gs[0][0] + (t & 1) * 4096;
    const short* ls = &Ls[0][0] + (t & 1) * 4096;

    frag8 af[4], gf[4], lf[4];
#pragma unroll
    for (int mi = 0; mi < 4; ++mi)
      af[mi] = *(const frag8*)&as[(wm + mi * 16 + fr) * 32 + fq];
#pragma unroll
    for (int ni = 0; ni < 4; ++ni) {
      gf[ni] = *(const frag8*)&gs[(wn + ni * 16 + fr) * 32 + fq];
      lf[ni] = *(const frag8*)&ls[(wn + ni * 16 + fr) * 32 + fq];
    }
#pragma unroll
    for (int mi = 0; mi < 4; ++mi)
#pragma unroll
      for (int ni = 0; ni < 4; ++ni) {
        accg[mi][ni] = __builtin_amdgcn_mfma_f32_16x16x32_bf16(
            af[mi], gf[ni], accg[mi][ni], 0, 0, 0);
        accl[mi][ni] = __builtin_amdgcn_mfma_f32_16x16x32_bf16(
            af[mi], lf[ni], accl[mi][ni], 0, 0, 0);
      }
    if (t + 1 < nt) bwrite((t + 1) & 1);
    __syncthreads();
  }

  const int er = (lane >> 4) * 4;
  const int ec = lane & 15;
#pragma unroll
  for (int mi = 0; mi < 4; ++mi)
#pragma unroll
    for (int ni = 0; ni < 4; ++ni)
#pragma unroll
      for (int r2 = 0; r2 < 4; ++r2) {
        int m = bm + wm + mi * 16 + er + r2;
        int n = bn + wn + ni * 16 + ec;
        size_t o = (size_t)m * N + n;
        float g = accg[mi][ni][r2] + gbias[n];
        float l = accl[mi][ni][r2] + lbias[n];
        float sig = 1.0f / (1.0f + __expf(-g));
        ((ushortt*)Cv)[o] = f2bu(sig * l);
      }
}

// ---------------------------------------------------------------------------
// FF-out GEMM, split-K (2 blocks per tile, KB=1024 each) + on-the-fly
// fp32->bf16 B staging. Grid 512 = 2 blocks/CU. Atomic fp32 accumulate into
// zero-initialized C (also accumulates across the 2 N-chunks).
// A = ffc bf16 [M][2048]; B = ff_out_w fp32 [1024][FFDIM], cols koff+kz*1024.
// ---------------------------------------------------------------------------
__global__ __launch_bounds__(256) void gemm_ffout(
    const ushortt* __restrict__ A, const float* __restrict__ Bw,
    float* __restrict__ C, int koff) {
  __shared__ __align__(16) short As[2][128 * 32];
  __shared__ __align__(16) short Bs[2][128 * 32];
  const int tid = threadIdx.x;
  const int wave = tid >> 6;
  const int lane = tid & 63;
  int xcd = blockIdx.x & 7, r = blockIdx.x >> 3;
  const int kz = r & 1; r >>= 1;
  const int bm = (xcd * 4 + (r & 3)) * 128;
  const int bn = (r >> 2) * 128;
  const int wm = (wave >> 1) * 64;
  const int wn = (wave & 1) * 64;

  f32x4 acc[4][4] = {};

  const int sr = lane >> 2;
  const int sc = (lane & 3) * 8;
  const ushortt* pa0 = A + (size_t)(bm + wave * 16 + sr) * 2048 + kz * 1024 + sc;
  const ushortt* pa1 = pa0 + (size_t)64 * 2048;
  const int lo0 = (wave * 16) * 32;
  const int lo1 = (64 + wave * 16) * 32;

  const int br = tid >> 2;
  const int kc = (tid & 3) * 8;
  const float* pb0 = Bw + (size_t)(bn + br) * FFDIM + koff + kz * 1024 + kc;
  const float* pb1 = pb0 + (size_t)64 * FFDIM;

  const int fr = lane & 15;
  const int fq = (lane >> 4) * 8;
  const int nt = 1024 >> 5;  // 32

  float4 f0, f1, f2, f3;
  auto bload = [&](int t) {
    const float* p0 = pb0 + t * 32;
    const float* p1 = pb1 + t * 32;
    f0 = *(const float4*)p0; f1 = *(const float4*)(p0 + 4);
    f2 = *(const float4*)p1; f3 = *(const float4*)(p1 + 4);
  };
  auto pk = [&](float4 a, float4 b) {
    frag8 v;
    v[0] = (short)f2bu(a.x); v[1] = (short)f2bu(a.y);
    v[2] = (short)f2bu(a.z); v[3] = (short)f2bu(a.w);
    v[4] = (short)f2bu(b.x); v[5] = (short)f2bu(b.y);
    v[6] = (short)f2bu(b.z); v[7] = (short)f2bu(b.w);
    return v;
  };
  auto bwrite = [&](int buf) {
    *(frag8*)&Bs[buf][tid * 8] = pk(f0, f1);
    *(frag8*)&Bs[buf][2048 + tid * 8] = pk(f2, f3);
  };
  auto astage = [&](int t, int buf) {
    const int ko = t * 32;
    short* ab = &As[0][0] + buf * 4096;
    __builtin_amdgcn_global_load_lds(
        (const __attribute__((address_space(1))) void*)(pa0 + ko),
        (__attribute__((address_space(3))) void*)(ab + lo0), 16, 0, 0);
    __builtin_amdgcn_global_load_lds(
        (const __attribute__((address_space(1))) void*)(pa1 + ko),
        (__attribute__((address_space(3))) void*)(ab + lo1), 16, 0, 0);
  };

  astage(0, 0);
  bload(0);
  bwrite(0);
  __syncthreads();

  for (int t = 0; t < nt; ++t) {
    if (t + 1 < nt) {
      astage(t + 1, (t + 1) & 1);
      bload(t + 1);
    }
    const short* as = &As[0][0] + (t & 1) * 4096;
    const short* bs = &Bs[0][0] + (t & 1) * 4096;

    frag8 af[4], bf[4];
#pragma unroll
    for (int mi = 0; mi < 4; ++mi)
      af[mi] = *(const frag8*)&as[(wm + mi * 16 + fr) * 32 + fq];
#pragma unroll
    for (int ni = 0; ni < 4; ++ni)
      bf[ni] = *(const frag8*)&bs[(wn + ni * 16 + fr) * 32 + fq];
#pragma unroll
    for (int mi = 0; mi < 4; ++mi)
#pragma unroll
      for (int ni = 0; ni < 4; ++ni)
        acc[mi][ni] = __builtin_amdgcn_mfma_f32_16x16x32_bf16(
            af[mi], bf[ni], acc[mi][ni], 0, 0, 0);
    if (t + 1 < nt) bwrite((t + 1) & 1);
    __syncthreads();
  }

  const int er = (lane >> 4) * 4;
  const int ec = lane & 15;
#pragma unroll
  for (int mi = 0; mi < 4; ++mi)
#pragma unroll
    for (int ni = 0; ni < 4; ++ni)
#pragma unroll
      for (int r2 = 0; r2 < 4; ++r2) {
        int m = bm + wm + mi * 16 + er + r2;
        int n = bn + wn + ni * 16 + ec;
        unsafeAtomicAdd(C + (size_t)m * 1024 + n, acc[mi][ni][r2]);
      }
}

// ---------------------------------------------------------------------------
// RoPE prep: qkv (B,S,3,H,D) bf16 -> Qr,Kr [bh][S][64] (Q scaled 1/8),
// Vr chunk-blocked [bh][S/64][64 d][64 key] (transposed per 64-seq chunk).
// ---------------------------------------------------------------------------
__global__ __launch_bounds__(256) void rope_prep(
    const ushortt* __restrict__ qkv, ushortt* __restrict__ Qr,
    ushortt* __restrict__ Kr, ushortt* __restrict__ Vr) {
  const int s0 = blockIdx.x * 64;
  const int bh = blockIdx.y;
  const int b = bh >> 4, h = bh & 15;
  const int tid = threadIdx.x;
  __shared__ float ifr_s[32];
  __shared__ ushortt vt[64][72];
  if (tid < 32) ifr_s[tid] = __powf(10000.0f, -(float)tid * (1.0f / 32.0f));
  __syncthreads();
  const size_t qbase = (size_t)bh * SEQ * 64;

#pragma unroll
  for (int i = 0; i < 8; ++i) {
    int p = i * 256 + tid;
    int r = p >> 5, d = p & 31;
    size_t src = ((size_t)(b * SEQ + s0 + r)) * (3 * DIMSZ) + h * 64 + d;
    float q1 = u2f(qkv[src]), q2 = u2f(qkv[src + 32]);
    float k1 = u2f(qkv[src + DIMSZ]), k2 = u2f(qkv[src + DIMSZ + 32]);
    float ang = (float)(s0 + r) * ifr_s[d];
    float sn, cs;
    __sincosf(ang, &sn, &cs);
    size_t dst = qbase + (size_t)(s0 + r) * 64 + d;
    Qr[dst]      = f2bu((q1 * cs - q2 * sn) * 0.125f);
    Qr[dst + 32] = f2bu((q1 * sn + q2 * cs) * 0.125f);
    Kr[dst]      = f2bu(k1 * cs - k2 * sn);
    Kr[dst + 32] = f2bu(k1 * sn + k2 * cs);
  }

#pragma unroll
  for (int i = 0; i < 2; ++i) {
    int e = (i * 256 + tid) * 8;
    int r = e >> 6, d0 = e & 63;
    size_t src = ((size_t)(b * SEQ + s0 + r)) * (3 * DIMSZ) + 2 * DIMSZ + h * 64 + d0;
    *(ushort4*)&vt[r][d0]     = *(const ushort4*)(qkv + src);
    *(ushort4*)&vt[r][d0 + 4] = *(const ushort4*)(qkv + src + 4);
  }
  __syncthreads();
  {
    int d = tid >> 2;
    int sc0 = (tid & 3) * 16;
    size_t dst = (size_t)bh * 64 * SEQ + (size_t)blockIdx.x * 4096 +
                 (size_t)d * 64 + sc0;
    ushortt tmp[16];
#pragma unroll
    for (int j = 0; j < 16; ++j) tmp[j] = vt[sc0 + j][d];
    *(ushort4*)(Vr + dst)      = *(ushort4*)&tmp[0];
    *(ushort4*)(Vr + dst + 4)  = *(ushort4*)&tmp[4];
    *(ushort4*)(Vr + dst + 8)  = *(ushort4*)&tmp[8];
    *(ushort4*)(Vr + dst + 12) = *(ushort4*)&tmp[12];
  }
}

// ---------------------------------------------------------------------------
// MFMA flash attention, LDS-staged K/V with double-buffered prefetch.
// 1D grid of 512 blocks; decode pairs qt q with 15-q across halves: per-CU
// cost constant (34), same bh on both co-resident blocks (L2 sharing).
// XOR-swizzle byte^=((row&7)<<4) on both sides (rule #21).
// ---------------------------------------------------------------------------
__global__ __launch_bounds__(512) void flash_mfma(
    const ushortt* __restrict__ Qr, const ushortt* __restrict__ Kr,
    const ushortt* __restrict__ Vr, ushortt* __restrict__ ctx) {
  const int id = blockIdx.x;
  const int r5 = id & 255;
  const int qt0 = r5 >> 5;
  const int qt = (id & 256) ? (15 - qt0) : qt0;   // balanced pairing
  const int bh = r5 & 31;
  const int q0 = qt * 128;
  const int b = bh >> 4, h = bh & 15;
  const int tid = threadIdx.x;
  const int w = tid >> 6;
  const int lane = tid & 63;
  const int fr = lane & 15;
  const int quad = lane >> 4;

  __shared__ __align__(16) short Kb[2][4096];
  __shared__ __align__(16) short Vb[2][4096];
  __shared__ __align__(16) ushortt Ps[8][16][72];

  const size_t qkbase = (size_t)bh * SEQ * 64;
  const size_t vbase = (size_t)bh * 64 * SEQ;

  const int lin = (w << 10) + ((lane & 63) << 4);
  const int swz = lin ^ (((lin >> 7) & 7) << 4);
  const char* ksrc = (const char*)(Kr + qkbase) + swz;
  const char* vsrc = (const char*)(Vr + vbase) + swz;
  short* kdst[2] = {&Kb[0][w * 512], &Kb[1][w * 512]};
  short* vdst[2] = {&Vb[0][w * 512], &Vb[1][w * 512]};

  frag8 aq[2];
#pragma unroll
  for (int hh = 0; hh < 2; ++hh)
    aq[hh] = *(const frag8*)(Qr + qkbase + (size_t)(q0 + w * 16 + fr) * 64 +
                             hh * 32 + quad * 8);

  float mr[4], lr[4];
  f32x4 od[4] = {};
#pragma unroll
  for (int r = 0; r < 4; ++r) { mr[r] = -1e30f; lr[r] = 0.0f; }

  const int nt = 2 * qt + 2;

  __builtin_amdgcn_global_load_lds(
      (const __attribute__((address_space(1))) void*)ksrc,
      (__attribute__((address_space(3))) void*)kdst[0], 16, 0, 0);
  __builtin_amdgcn_global_load_lds(
      (const __attribute__((address_space(1))) void*)vsrc,
      (__attribute__((address_space(3))) void*)vdst[0], 16, 0, 0);
  __syncthreads();

  for (int t = 0; t < nt; ++t) {
    const int c0 = t * 64;
    if (t + 1 < nt) {
      const char* kn = ksrc + (size_t)(t + 1) * 8192;
      const char* vn = vsrc + (size_t)(t + 1) * 8192;
      __builtin_amdgcn_global_load_lds(
          (const __attribute__((address_space(1))) void*)kn,
          (__attribute__((address_space(3))) void*)kdst[(t + 1) & 1], 16, 0, 0);
      __builtin_amdgcn_global_load_lds(
          (const __attribute__((address_space(1))) void*)vn,
          (__attribute__((address_space(3))) void*)vdst[(t + 1) & 1], 16, 0, 0);
    }
    const char* kcur = (const char*)Kb[t & 1];
    const char* vcur = (const char*)Vb[t & 1];

    if (c0 <= q0 + w * 16 + 15) {
      f32x4 sc[4] = {};
#pragma unroll
      for (int ni = 0; ni < 4; ++ni)
#pragma unroll
        for (int hh = 0; hh < 2; ++hh) {
          int kb = (((ni * 16 + fr) << 7) + (hh << 6) + (quad << 4)) ^
                   ((fr & 7) << 4);
          frag8 kf = *(const frag8*)(kcur + kb);
          sc[ni] = __builtin_amdgcn_mfma_f32_16x16x32_bf16(aq[hh], kf, sc[ni],
                                                           0, 0, 0);
        }

      if (c0 + 63 > q0 + w * 16) {
        int rowb = q0 + w * 16 + quad * 4;
#pragma unroll
        for (int ni = 0; ni < 4; ++ni) {
          int col = c0 + ni * 16 + fr;
#pragma unroll
          for (int r = 0; r < 4; ++r)
            if (col > rowb + r) sc[ni][r] = -1e30f;
        }
      }

#pragma unroll
      for (int r = 0; r < 4; ++r) {
        float cm = fmaxf(fmaxf(sc[0][r], sc[1][r]), fmaxf(sc[2][r], sc[3][r]));
        for (int off = 1; off < 16; off <<= 1)
          cm = fmaxf(cm, __shfl_xor(cm, off, 16));
        float mn = fmaxf(mr[r], cm);
        float corr = __expf(mr[r] - mn);
        mr[r] = mn;
        float ps = 0.0f;
#pragma unroll
        for (int ni = 0; ni < 4; ++ni) {
          float p = __expf(sc[ni][r] - mn);
          Ps[w][quad * 4 + r][ni * 16 + fr] = f2bu(p);
          ps += p;
        }
        for (int off = 1; off < 16; off <<= 1) ps += __shfl_xor(ps, off, 16);
        lr[r] = lr[r] * corr + ps;
#pragma unroll
        for (int dt = 0; dt < 4; ++dt) od[dt][r] *= corr;
      }

      frag8 pf[2];
#pragma unroll
      for (int hh = 0; hh < 2; ++hh)
        pf[hh] = *(const frag8*)&Ps[w][fr][hh * 32 + quad * 8];
#pragma unroll
      for (int dt = 0; dt < 4; ++dt)
#pragma unroll
        for (int hh = 0; hh < 2; ++hh) {
          int vb_ = (((dt * 16 + fr) << 7) + (hh << 6) + (quad << 4)) ^
                    ((fr & 7) << 4);
          frag8 vf = *(const frag8*)(vcur + vb_);
          od[dt] = __builtin_amdgcn_mfma_f32_16x16x32_bf16(pf[hh], vf, od[dt],
                                                           0, 0, 0);
        }
    }
    __syncthreads();
  }

#pragma unroll
  for (int r = 0; r < 4; ++r) {
    float inv = 1.0f / lr[r];
    size_t row = (size_t)(b * SEQ + q0 + w * 16 + quad * 4 + r) * DIMSZ + h * 64;
#pragma unroll
    for (int dt = 0; dt < 4; ++dt)
      ctx[row + dt * 16 + fr] = f2bu(od[dt][r] * inv);
  }
}

// ---------------------------------------------------------------------------
// y = res + proj; out = scale * y / (||y||*D^-0.5 + eps). One block per row.
// DUAL=1 also writes bf16 copy (GEMM A operand).
// ---------------------------------------------------------------------------
template <int DUAL>
__global__ __launch_bounds__(256) void add_rmsnorm(
    const float* __restrict__ res, const float* __restrict__ proj,
    const float* __restrict__ scale, float* __restrict__ out,
    ushortt* __restrict__ out2) {
  const int row = blockIdx.x;
  const int tid = threadIdx.x;
  const size_t base = (size_t)row * DIMSZ;
  __shared__ float red[4];
  float y[4];
  float ss = 0.0f;
#pragma unroll
  for (int j = 0; j < 4; ++j) {
    int d = tid + j * 256;
    float yv = res[base + d] + proj[base + d];
    y[j] = yv;
    ss += yv * yv;
  }
  for (int off = 1; off < 64; off <<= 1) ss += __shfl_xor(ss, off, 64);
  if ((tid & 63) == 0) red[tid >> 6] = ss;
  __syncthreads();
  float tot = red[0] + red[1] + red[2] + red[3];
  float norm = sqrtf(tot) * 0.03125f;
  float inv = 1.0f / (norm + 1e-8f);
#pragma unroll
  for (int j = 0; j < 4; ++j) {
    int d = tid + j * 256;
    float v = scale[d] * y[j] * inv;
    out[base + d] = v;
    if (DUAL) out2[base + d] = f2bu(v);
  }
}

// ---------------------------------------------------------------------------
extern "C" void kernel_launch(void* const* d_in, const int* in_sizes, int n_in,
                              void* d_out, int out_size, void* d_ws, size_t ws_size,
                              hipStream_t stream) {
  const float* x          = (const float*)d_in[0];
  // d_in[1] = causal mask (bool) — structure hardcoded, unused
  const float* qkv_w      = (const float*)d_in[2];
  const float* attn_out_w = (const float*)d_in[3];
  const float* gate_w     = (const float*)d_in[4];
  const float* gate_b     = (const float*)d_in[5];
  const float* lin_w      = (const float*)d_in[6];
  const float* lin_b      = (const float*)d_in[7];
  const float* ff_out_w   = (const float*)d_in[8];
  const float* n1s        = (const float*)d_in[9];
  const float* n2s        = (const float*)d_in[10];
  float* out = (float*)d_out;

  const int M = NBATCH * SEQ;  // 4096
  char* ws = (char*)d_ws;
  char* dob = (char*)d_out;
  const size_t MB = 1 << 20;
  // ws layout (bytes), lifetime-disjoint; high-water 48 MB:
  ushortt* qkv_tmp = (ushortt*)(ws + 0);        // [0,24)  bf16, p1..rope
  ushortt* xb      = (ushortt*)(ws + 24 * MB);  // [24,32) bf16, p1 (pre-Qr)
  ushortt* qkv_wb  = (ushortt*)(ws + 32 * MB);  // [32,38) bf16, p1 (pre-Kr)
  ushortt* Qr      = (ushortt*)(ws + 24 * MB);  // [24,32) bf16, rope..attn
  ushortt* Kr      = (ushortt*)(ws + 32 * MB);  // [32,40) bf16, rope..attn
  ushortt* Vr      = (ushortt*)(ws + 40 * MB);  // [40,48) bf16, rope..attn
  ushortt* attn_wb = (ushortt*)(ws + 24 * MB);  // [24,26) bf16, p3 (Qr dead)
  float*   proj    = (float*)(ws + 0);          // [0,16)  fp32, p3..p4
  float*   x1      = (float*)(ws + 16 * MB);    // [16,32) fp32, p4..end
  ushortt* x1b     = (ushortt*)(ws + 32 * MB);  // [32,40) bf16, p4..end
  float*   proj2   = (float*)(ws + 0);          // [0,16)  fp32, p5..end
  // d_out doubles as scratch:
  ushortt* ctx  = (ushortt*)(dob + 0);          // [0,8)  bf16, p2..p3
  ushortt* ffc  = (ushortt*)(dob + 0);          // [0,16) bf16, p5 chunk

  // p1: casts + qkv GEMM (bf16 out)
  cast_f2b<<<4194304 / 1024, 256, 0, stream>>>(x, xb, 4194304);
  cast_f2b<<<3145728 / 1024, 256, 0, stream>>>(qkv_w, qkv_wb, 3145728);
  gemm_mfma<1, 1><<<(3072 / 128) * 32, 256, 0, stream>>>(
      xb, qkv_wb, qkv_tmp, M, 3072, DIMSZ, DIMSZ);
  // p2: RoPE prep + MFMA flash attention (balanced 1D grid)
  rope_prep<<<dim3(SEQ / 64, NBATCH * NHEAD), 256, 0, stream>>>(
      qkv_tmp, Qr, Kr, Vr);
  flash_mfma<<<(SEQ / 128) * NBATCH * NHEAD, 512, 0, stream>>>(
      Qr, Kr, Vr, ctx);
  // p3: attn projection, split-K 2 (512 blocks = 2/CU), atomic accumulate
  cast_f2b<<<1048576 / 1024, 256, 0, stream>>>(attn_out_w, attn_wb, 1048576);
  zero_f32<<<4194304 / 1024, 256, 0, stream>>>(proj, 4194304);
  gemm_mfma<2, 2><<<(DIMSZ / 128) * 32 * 2, 256, 0, stream>>>(
      ctx, attn_wb, proj, M, DIMSZ, DIMSZ, 512);
  // p4: x1 = rmsnorm(x + proj), fp32 + bf16 copies
  add_rmsnorm<1><<<M, 256, 0, stream>>>(x, proj, n1s, x1, x1b);
  // p5: FF in 2 chunks of 2048; gatelin casts fp32 B on the fly; ffout
  // split-K 2 + atomic accumulate into zeroed proj2.
  zero_f32<<<4194304 / 1024, 256, 0, stream>>>(proj2, 4194304);
  for (int c = 0; c < 2; ++c) {
    gemm_gatelin<<<(2048 / 128) * 32, 256, 0, stream>>>(
        x1b, gate_w + (size_t)c * 2097152, lin_w + (size_t)c * 2097152,
        ffc, gate_b + c * 2048, lin_b + c * 2048, M, 2048, DIMSZ);
    gemm_ffout<<<(1024 / 128) * 32 * 2, 256, 0, stream>>>(
        ffc, ff_out_w, proj2, c * 2048);
  }
  // p6: out = rmsnorm(x1 + proj2)
  add_rmsnorm<0><<<M, 256, 0, stream>>>(x1, proj2, n2s, out, nullptr);
}

// Round 8
// 563.902 us; speedup vs baseline: 1.1695x; 1.1695x over previous
//
#include <hip/hip_runtime.h>
#include <hip/hip_bf16.h>
#include <math.h>

#define DIMSZ 1024
#define NHEAD 16
#define HDIM 64
#define FFDIM 4096
#define SEQ 2048
#define NBATCH 2

typedef unsigned short ushortt;
typedef __attribute__((ext_vector_type(8))) short frag8;   // 8 bf16 (4 VGPR)
typedef __attribute__((ext_vector_type(4))) float f32x4;   // MFMA acc

// bf16 (stored as ushort) <-> fp32
__device__ __forceinline__ float u2f(ushortt u) {
  return __uint_as_float(((unsigned)u) << 16);
}
__device__ __forceinline__ ushortt f2bu(float f) {  // RNE
  unsigned x = __float_as_uint(f);
  return (ushortt)((x + 0x7FFFu + ((x >> 16) & 1u)) >> 16);
}

// ---------------------------------------------------------------------------
// fp32 -> bf16 cast, 4 elems/thread, n % 4 == 0
// ---------------------------------------------------------------------------
__global__ __launch_bounds__(256) void cast_f2b(
    const float* __restrict__ src, ushortt* __restrict__ dst, int n) {
  int i = (blockIdx.x * 256 + threadIdx.x) * 4;
  if (i >= n) return;
  float4 f = *(const float4*)(src + i);
  ushort4 u;
  u.x = f2bu(f.x); u.y = f2bu(f.y); u.z = f2bu(f.z); u.w = f2bu(f.w);
  *(ushort4*)(dst + i) = u;
}

// ---------------------------------------------------------------------------
// zero fp32 buffer (pre-pass for atomic-accumulate GEMMs), n % 4 == 0
// ---------------------------------------------------------------------------
__global__ __launch_bounds__(256) void zero_f32(float* __restrict__ p, int n) {
  int i = (blockIdx.x * 256 + threadIdx.x) * 4;
  if (i < n) *(float4*)(p + i) = make_float4(0.f, 0.f, 0.f, 0.f);
}

// ---------------------------------------------------------------------------
// MFMA GEMM, double-buffered (STAGE(t+1) before compute(t), 1 barrier/K-step).
// 1D grid, XCD-grouped decode (id%8 = XCD; 4 y-panels per XCD -> A stays in
// that XCD's L2). SK=2: 2 blocks per output tile handle disjoint K-halves
// (KB each); kz=1 writes to C + skoff (disjoint buffer, NO atomics) -- the
// consumer (add_rmsnorm NP=3) sums the two partials.
// EPI: 0 fp32 store | 1 bf16 store
// ---------------------------------------------------------------------------
template <int EPI, int SK>
__global__ __launch_bounds__(256) void gemm_mfma(
    const ushortt* __restrict__ A, const ushortt* __restrict__ W,
    void* __restrict__ Cv, int M, int N, int K, int KB, size_t skoff) {
  __shared__ __align__(16) short As[2][128 * 32];
  __shared__ __align__(16) short Bs[2][128 * 32];
  const int tid = threadIdx.x;
  const int wave = tid >> 6;
  const int lane = tid & 63;
  int xcd = blockIdx.x & 7, r = blockIdx.x >> 3, kz = 0;
  if (SK == 2) { kz = r & 1; r >>= 1; }
  const int bm = (xcd * 4 + (r & 3)) * 128;
  const int bn = (r >> 2) * 128;
  const int ko0 = kz * KB;
  const int wm = (wave >> 1) * 64;
  const int wn = (wave & 1) * 64;

  f32x4 acc[4][4] = {};

  const int sr = lane >> 2;
  const int sc = (lane & 3) * 8;
  const ushortt* pa0 = A + (size_t)(bm + wave * 16 + sr) * K + ko0 + sc;
  const ushortt* pa1 = pa0 + (size_t)64 * K;
  const ushortt* pb0 = W + (size_t)(bn + wave * 16 + sr) * K + ko0 + sc;
  const ushortt* pb1 = pb0 + (size_t)64 * K;
  const int lo0 = (wave * 16) * 32;
  const int lo1 = (64 + wave * 16) * 32;

  const int fr = lane & 15;
  const int fq = (lane >> 4) * 8;
  const int nt = KB >> 5;

  auto stage = [&](int t, int buf) {
    const int ko = t * 32;
    short* ab = &As[0][0] + buf * 4096;
    short* bb = &Bs[0][0] + buf * 4096;
    __builtin_amdgcn_global_load_lds(
        (const __attribute__((address_space(1))) void*)(pa0 + ko),
        (__attribute__((address_space(3))) void*)(ab + lo0), 16, 0, 0);
    __builtin_amdgcn_global_load_lds(
        (const __attribute__((address_space(1))) void*)(pa1 + ko),
        (__attribute__((address_space(3))) void*)(ab + lo1), 16, 0, 0);
    __builtin_amdgcn_global_load_lds(
        (const __attribute__((address_space(1))) void*)(pb0 + ko),
        (__attribute__((address_space(3))) void*)(bb + lo0), 16, 0, 0);
    __builtin_amdgcn_global_load_lds(
        (const __attribute__((address_space(1))) void*)(pb1 + ko),
        (__attribute__((address_space(3))) void*)(bb + lo1), 16, 0, 0);
  };

  stage(0, 0);
  __syncthreads();

  for (int t = 0; t < nt; ++t) {
    if (t + 1 < nt) stage(t + 1, (t + 1) & 1);
    const short* as = &As[0][0] + (t & 1) * 4096;
    const short* bs = &Bs[0][0] + (t & 1) * 4096;

    frag8 af[4], bf[4];
#pragma unroll
    for (int mi = 0; mi < 4; ++mi)
      af[mi] = *(const frag8*)&as[(wm + mi * 16 + fr) * 32 + fq];
#pragma unroll
    for (int ni = 0; ni < 4; ++ni)
      bf[ni] = *(const frag8*)&bs[(wn + ni * 16 + fr) * 32 + fq];
#pragma unroll
    for (int mi = 0; mi < 4; ++mi)
#pragma unroll
      for (int ni = 0; ni < 4; ++ni)
        acc[mi][ni] = __builtin_amdgcn_mfma_f32_16x16x32_bf16(
            af[mi], bf[ni], acc[mi][ni], 0, 0, 0);
    __syncthreads();
  }

  const int er = (lane >> 4) * 4;
  const int ec = lane & 15;
  float* C0 = (float*)Cv + (SK == 2 ? (size_t)kz * skoff : 0);
#pragma unroll
  for (int mi = 0; mi < 4; ++mi)
#pragma unroll
    for (int ni = 0; ni < 4; ++ni)
#pragma unroll
      for (int r2 = 0; r2 < 4; ++r2) {
        int m = bm + wm + mi * 16 + er + r2;
        int n = bn + wn + ni * 16 + ec;
        size_t o = (size_t)m * N + n;
        float v = acc[mi][ni][r2];
        if (EPI == 0) {
          C0[o] = v;
        } else {
          ((ushortt*)Cv)[o] = f2bu(v);
        }
      }
}

// ---------------------------------------------------------------------------
// Fused gate+lin GEMM (round-6 form): one staged A tile feeds TWO pre-cast
// bf16 B tiles via global_load_lds; 32 MFMA/K-step, dual accumulators.
// Epilogue: out = sigmoid(g+gbias)*(l+lbias) -> bf16.
// ---------------------------------------------------------------------------
__global__ __launch_bounds__(256) void gemm_gatelin(
    const ushortt* __restrict__ A, const ushortt* __restrict__ Wg,
    const ushortt* __restrict__ Wl, ushortt* __restrict__ Cv,
    const float* __restrict__ gbias, const float* __restrict__ lbias,
    int M, int N, int K) {
  __shared__ __align__(16) short As[2][128 * 32];
  __shared__ __align__(16) short Gs[2][128 * 32];
  __shared__ __align__(16) short Ls[2][128 * 32];
  const int tid = threadIdx.x;
  const int wave = tid >> 6;
  const int lane = tid & 63;
  int xcd = blockIdx.x & 7, r = blockIdx.x >> 3;
  const int bm = (xcd * 4 + (r & 3)) * 128;
  const int bn = (r >> 2) * 128;
  const int wm = (wave >> 1) * 64;
  const int wn = (wave & 1) * 64;

  f32x4 accg[4][4] = {};
  f32x4 accl[4][4] = {};

  const int sr = lane >> 2;
  const int sc = (lane & 3) * 8;
  const ushortt* pa0 = A + (size_t)(bm + wave * 16 + sr) * K + sc;
  const ushortt* pa1 = pa0 + (size_t)64 * K;
  const ushortt* pg0 = Wg + (size_t)(bn + wave * 16 + sr) * K + sc;
  const ushortt* pg1 = pg0 + (size_t)64 * K;
  const ushortt* pl0 = Wl + (size_t)(bn + wave * 16 + sr) * K + sc;
  const ushortt* pl1 = pl0 + (size_t)64 * K;
  const int lo0 = (wave * 16) * 32;
  const int lo1 = (64 + wave * 16) * 32;

  const int fr = lane & 15;
  const int fq = (lane >> 4) * 8;
  const int nt = K >> 5;

  auto stage = [&](int t, int buf) {
    const int ko = t * 32;
    short* ab = &As[0][0] + buf * 4096;
    short* gb = &Gs[0][0] + buf * 4096;
    short* lb = &Ls[0][0] + buf * 4096;
    __builtin_amdgcn_global_load_lds(
        (const __attribute__((address_space(1))) void*)(pa0 + ko),
        (__attribute__((address_space(3))) void*)(ab + lo0), 16, 0, 0);
    __builtin_amdgcn_global_load_lds(
        (const __attribute__((address_space(1))) void*)(pa1 + ko),
        (__attribute__((address_space(3))) void*)(ab + lo1), 16, 0, 0);
    __builtin_amdgcn_global_load_lds(
        (const __attribute__((address_space(1))) void*)(pg0 + ko),
        (__attribute__((address_space(3))) void*)(gb + lo0), 16, 0, 0);
    __builtin_amdgcn_global_load_lds(
        (const __attribute__((address_space(1))) void*)(pg1 + ko),
        (__attribute__((address_space(3))) void*)(gb + lo1), 16, 0, 0);
    __builtin_amdgcn_global_load_lds(
        (const __attribute__((address_space(1))) void*)(pl0 + ko),
        (__attribute__((address_space(3))) void*)(lb + lo0), 16, 0, 0);
    __builtin_amdgcn_global_load_lds(
        (const __attribute__((address_space(1))) void*)(pl1 + ko),
        (__attribute__((address_space(3))) void*)(lb + lo1), 16, 0, 0);
  };

  stage(0, 0);
  __syncthreads();

  for (int t = 0; t < nt; ++t) {
    if (t + 1 < nt) stage(t + 1, (t + 1) & 1);
    const short* as = &As[0][0] + (t & 1) * 4096;
    const short* gs = &Gs[0][0] + (t & 1) * 4096;
    const short* ls = &Ls[0][0] + (t & 1) * 4096;

    frag8 af[4], gf[4], lf[4];
#pragma unroll
    for (int mi = 0; mi < 4; ++mi)
      af[mi] = *(const frag8*)&as[(wm + mi * 16 + fr) * 32 + fq];
#pragma unroll
    for (int ni = 0; ni < 4; ++ni) {
      gf[ni] = *(const frag8*)&gs[(wn + ni * 16 + fr) * 32 + fq];
      lf[ni] = *(const frag8*)&ls[(wn + ni * 16 + fr) * 32 + fq];
    }
#pragma unroll
    for (int mi = 0; mi < 4; ++mi)
#pragma unroll
      for (int ni = 0; ni < 4; ++ni) {
        accg[mi][ni] = __builtin_amdgcn_mfma_f32_16x16x32_bf16(
            af[mi], gf[ni], accg[mi][ni], 0, 0, 0);
        accl[mi][ni] = __builtin_amdgcn_mfma_f32_16x16x32_bf16(
            af[mi], lf[ni], accl[mi][ni], 0, 0, 0);
      }
    __syncthreads();
  }

  const int er = (lane >> 4) * 4;
  const int ec = lane & 15;
#pragma unroll
  for (int mi = 0; mi < 4; ++mi)
#pragma unroll
    for (int ni = 0; ni < 4; ++ni)
#pragma unroll
      for (int r2 = 0; r2 < 4; ++r2) {
        int m = bm + wm + mi * 16 + er + r2;
        int n = bn + wn + ni * 16 + ec;
        size_t o = (size_t)m * N + n;
        float g = accg[mi][ni][r2] + gbias[n];
        float l = accl[mi][ni][r2] + lbias[n];
        float sig = 1.0f / (1.0f + __expf(-g));
        ((ushortt*)Cv)[o] = f2bu(sig * l);
      }
}

// ---------------------------------------------------------------------------
// FF-out GEMM, split-K (2 blocks per tile, KB=1024) + on-the-fly fp32->bf16
// B staging (per-kz B slice = 4 MB, L2-resident). Grid 512 = 2 blocks/CU.
// Atomic fp32 accumulate into zero-initialized C (across 2 chunks x 2 kz).
// A = ffc bf16 [M][2048]; B = ff_out_w fp32 [1024][FFDIM], cols koff+kz*1024.
// ---------------------------------------------------------------------------
__global__ __launch_bounds__(256) void gemm_ffout(
    const ushortt* __restrict__ A, const float* __restrict__ Bw,
    float* __restrict__ C, int koff) {
  __shared__ __align__(16) short As[2][128 * 32];
  __shared__ __align__(16) short Bs[2][128 * 32];
  const int tid = threadIdx.x;
  const int wave = tid >> 6;
  const int lane = tid & 63;
  int xcd = blockIdx.x & 7, r = blockIdx.x >> 3;
  const int kz = r & 1; r >>= 1;
  const int bm = (xcd * 4 + (r & 3)) * 128;
  const int bn = (r >> 2) * 128;
  const int wm = (wave >> 1) * 64;
  const int wn = (wave & 1) * 64;

  f32x4 acc[4][4] = {};

  const int sr = lane >> 2;
  const int sc = (lane & 3) * 8;
  const ushortt* pa0 = A + (size_t)(bm + wave * 16 + sr) * 2048 + kz * 1024 + sc;
  const ushortt* pa1 = pa0 + (size_t)64 * 2048;
  const int lo0 = (wave * 16) * 32;
  const int lo1 = (64 + wave * 16) * 32;

  const int br = tid >> 2;
  const int kc = (tid & 3) * 8;
  const float* pb0 = Bw + (size_t)(bn + br) * FFDIM + koff + kz * 1024 + kc;
  const float* pb1 = pb0 + (size_t)64 * FFDIM;

  const int fr = lane & 15;
  const int fq = (lane >> 4) * 8;
  const int nt = 1024 >> 5;  // 32

  float4 f0, f1, f2, f3;
  auto bload = [&](int t) {
    const float* p0 = pb0 + t * 32;
    const float* p1 = pb1 + t * 32;
    f0 = *(const float4*)p0; f1 = *(const float4*)(p0 + 4);
    f2 = *(const float4*)p1; f3 = *(const float4*)(p1 + 4);
  };
  auto pk = [&](float4 a, float4 b) {
    frag8 v;
    v[0] = (short)f2bu(a.x); v[1] = (short)f2bu(a.y);
    v[2] = (short)f2bu(a.z); v[3] = (short)f2bu(a.w);
    v[4] = (short)f2bu(b.x); v[5] = (short)f2bu(b.y);
    v[6] = (short)f2bu(b.z); v[7] = (short)f2bu(b.w);
    return v;
  };
  auto bwrite = [&](int buf) {
    *(frag8*)&Bs[buf][tid * 8] = pk(f0, f1);
    *(frag8*)&Bs[buf][2048 + tid * 8] = pk(f2, f3);
  };
  auto astage = [&](int t, int buf) {
    const int ko = t * 32;
    short* ab = &As[0][0] + buf * 4096;
    __builtin_amdgcn_global_load_lds(
        (const __attribute__((address_space(1))) void*)(pa0 + ko),
        (__attribute__((address_space(3))) void*)(ab + lo0), 16, 0, 0);
    __builtin_amdgcn_global_load_lds(
        (const __attribute__((address_space(1))) void*)(pa1 + ko),
        (__attribute__((address_space(3))) void*)(ab + lo1), 16, 0, 0);
  };

  astage(0, 0);
  bload(0);
  bwrite(0);
  __syncthreads();

  for (int t = 0; t < nt; ++t) {
    if (t + 1 < nt) {
      astage(t + 1, (t + 1) & 1);
      bload(t + 1);
    }
    const short* as = &As[0][0] + (t & 1) * 4096;
    const short* bs = &Bs[0][0] + (t & 1) * 4096;

    frag8 af[4], bf[4];
#pragma unroll
    for (int mi = 0; mi < 4; ++mi)
      af[mi] = *(const frag8*)&as[(wm + mi * 16 + fr) * 32 + fq];
#pragma unroll
    for (int ni = 0; ni < 4; ++ni)
      bf[ni] = *(const frag8*)&bs[(wn + ni * 16 + fr) * 32 + fq];
#pragma unroll
    for (int mi = 0; mi < 4; ++mi)
#pragma unroll
      for (int ni = 0; ni < 4; ++ni)
        acc[mi][ni] = __builtin_amdgcn_mfma_f32_16x16x32_bf16(
            af[mi], bf[ni], acc[mi][ni], 0, 0, 0);
    if (t + 1 < nt) bwrite((t + 1) & 1);
    __syncthreads();
  }

  const int er = (lane >> 4) * 4;
  const int ec = lane & 15;
#pragma unroll
  for (int mi = 0; mi < 4; ++mi)
#pragma unroll
    for (int ni = 0; ni < 4; ++ni)
#pragma unroll
      for (int r2 = 0; r2 < 4; ++r2) {
        int m = bm + wm + mi * 16 + er + r2;
        int n = bn + wn + ni * 16 + ec;
        unsafeAtomicAdd(C + (size_t)m * 1024 + n, acc[mi][ni][r2]);
      }
}

// ---------------------------------------------------------------------------
// RoPE prep: qkv (B,S,3,H,D) bf16 -> Qr,Kr [bh][S][64] (Q scaled 1/8),
// Vr chunk-blocked [bh][S/64][64 d][64 key] (transposed per 64-seq chunk).
// ---------------------------------------------------------------------------
__global__ __launch_bounds__(256) void rope_prep(
    const ushortt* __restrict__ qkv, ushortt* __restrict__ Qr,
    ushortt* __restrict__ Kr, ushortt* __restrict__ Vr) {
  const int s0 = blockIdx.x * 64;
  const int bh = blockIdx.y;
  const int b = bh >> 4, h = bh & 15;
  const int tid = threadIdx.x;
  __shared__ float ifr_s[32];
  __shared__ ushortt vt[64][72];
  if (tid < 32) ifr_s[tid] = __powf(10000.0f, -(float)tid * (1.0f / 32.0f));
  __syncthreads();
  const size_t qbase = (size_t)bh * SEQ * 64;

#pragma unroll
  for (int i = 0; i < 8; ++i) {
    int p = i * 256 + tid;
    int r = p >> 5, d = p & 31;
    size_t src = ((size_t)(b * SEQ + s0 + r)) * (3 * DIMSZ) + h * 64 + d;
    float q1 = u2f(qkv[src]), q2 = u2f(qkv[src + 32]);
    float k1 = u2f(qkv[src + DIMSZ]), k2 = u2f(qkv[src + DIMSZ + 32]);
    float ang = (float)(s0 + r) * ifr_s[d];
    float sn, cs;
    __sincosf(ang, &sn, &cs);
    size_t dst = qbase + (size_t)(s0 + r) * 64 + d;
    Qr[dst]      = f2bu((q1 * cs - q2 * sn) * 0.125f);
    Qr[dst + 32] = f2bu((q1 * sn + q2 * cs) * 0.125f);
    Kr[dst]      = f2bu(k1 * cs - k2 * sn);
    Kr[dst + 32] = f2bu(k1 * sn + k2 * cs);
  }

#pragma unroll
  for (int i = 0; i < 2; ++i) {
    int e = (i * 256 + tid) * 8;
    int r = e >> 6, d0 = e & 63;
    size_t src = ((size_t)(b * SEQ + s0 + r)) * (3 * DIMSZ) + 2 * DIMSZ + h * 64 + d0;
    *(ushort4*)&vt[r][d0]     = *(const ushort4*)(qkv + src);
    *(ushort4*)&vt[r][d0 + 4] = *(const ushort4*)(qkv + src + 4);
  }
  __syncthreads();
  {
    int d = tid >> 2;
    int sc0 = (tid & 3) * 16;
    size_t dst = (size_t)bh * 64 * SEQ + (size_t)blockIdx.x * 4096 +
                 (size_t)d * 64 + sc0;
    ushortt tmp[16];
#pragma unroll
    for (int j = 0; j < 16; ++j) tmp[j] = vt[sc0 + j][d];
    *(ushort4*)(Vr + dst)      = *(ushort4*)&tmp[0];
    *(ushort4*)(Vr + dst + 4)  = *(ushort4*)&tmp[4];
    *(ushort4*)(Vr + dst + 8)  = *(ushort4*)&tmp[8];
    *(ushort4*)(Vr + dst + 12) = *(ushort4*)&tmp[12];
  }
}

// ---------------------------------------------------------------------------
// MFMA flash attention, LDS-staged K/V with double-buffered prefetch.
// 1D grid of 512 blocks; decode pairs qt q with 15-q across halves: per-CU
// cost constant (34), same bh on both co-resident blocks (L2 sharing).
// XOR-swizzle byte^=((row&7)<<4) on both sides (rule #21).
// ---------------------------------------------------------------------------
__global__ __launch_bounds__(512) void flash_mfma(
    const ushortt* __restrict__ Qr, const ushortt* __restrict__ Kr,
    const ushortt* __restrict__ Vr, ushortt* __restrict__ ctx) {
  const int id = blockIdx.x;
  const int r5 = id & 255;
  const int qt0 = r5 >> 5;
  const int qt = (id & 256) ? (15 - qt0) : qt0;   // balanced pairing
  const int bh = r5 & 31;
  const int q0 = qt * 128;
  const int b = bh >> 4, h = bh & 15;
  const int tid = threadIdx.x;
  const int w = tid >> 6;
  const int lane = tid & 63;
  const int fr = lane & 15;
  const int quad = lane >> 4;

  __shared__ __align__(16) short Kb[2][4096];
  __shared__ __align__(16) short Vb[2][4096];
  __shared__ __align__(16) ushortt Ps[8][16][72];

  const size_t qkbase = (size_t)bh * SEQ * 64;
  const size_t vbase = (size_t)bh * 64 * SEQ;

  const int lin = (w << 10) + ((lane & 63) << 4);
  const int swz = lin ^ (((lin >> 7) & 7) << 4);
  const char* ksrc = (const char*)(Kr + qkbase) + swz;
  const char* vsrc = (const char*)(Vr + vbase) + swz;
  short* kdst[2] = {&Kb[0][w * 512], &Kb[1][w * 512]};
  short* vdst[2] = {&Vb[0][w * 512], &Vb[1][w * 512]};

  frag8 aq[2];
#pragma unroll
  for (int hh = 0; hh < 2; ++hh)
    aq[hh] = *(const frag8*)(Qr + qkbase + (size_t)(q0 + w * 16 + fr) * 64 +
                             hh * 32 + quad * 8);

  float mr[4], lr[4];
  f32x4 od[4] = {};
#pragma unroll
  for (int r = 0; r < 4; ++r) { mr[r] = -1e30f; lr[r] = 0.0f; }

  const int nt = 2 * qt + 2;

  __builtin_amdgcn_global_load_lds(
      (const __attribute__((address_space(1))) void*)ksrc,
      (__attribute__((address_space(3))) void*)kdst[0], 16, 0, 0);
  __builtin_amdgcn_global_load_lds(
      (const __attribute__((address_space(1))) void*)vsrc,
      (__attribute__((address_space(3))) void*)vdst[0], 16, 0, 0);
  __syncthreads();

  for (int t = 0; t < nt; ++t) {
    const int c0 = t * 64;
    if (t + 1 < nt) {
      const char* kn = ksrc + (size_t)(t + 1) * 8192;
      const char* vn = vsrc + (size_t)(t + 1) * 8192;
      __builtin_amdgcn_global_load_lds(
          (const __attribute__((address_space(1))) void*)kn,
          (__attribute__((address_space(3))) void*)kdst[(t + 1) & 1], 16, 0, 0);
      __builtin_amdgcn_global_load_lds(
          (const __attribute__((address_space(1))) void*)vn,
          (__attribute__((address_space(3))) void*)vdst[(t + 1) & 1], 16, 0, 0);
    }
    const char* kcur = (const char*)Kb[t & 1];
    const char* vcur = (const char*)Vb[t & 1];

    if (c0 <= q0 + w * 16 + 15) {
      f32x4 sc[4] = {};
#pragma unroll
      for (int ni = 0; ni < 4; ++ni)
#pragma unroll
        for (int hh = 0; hh < 2; ++hh) {
          int kb = (((ni * 16 + fr) << 7) + (hh << 6) + (quad << 4)) ^
                   ((fr & 7) << 4);
          frag8 kf = *(const frag8*)(kcur + kb);
          sc[ni] = __builtin_amdgcn_mfma_f32_16x16x32_bf16(aq[hh], kf, sc[ni],
                                                           0, 0, 0);
        }

      if (c0 + 63 > q0 + w * 16) {
        int rowb = q0 + w * 16 + quad * 4;
#pragma unroll
        for (int ni = 0; ni < 4; ++ni) {
          int col = c0 + ni * 16 + fr;
#pragma unroll
          for (int r = 0; r < 4; ++r)
            if (col > rowb + r) sc[ni][r] = -1e30f;
        }
      }

#pragma unroll
      for (int r = 0; r < 4; ++r) {
        float cm = fmaxf(fmaxf(sc[0][r], sc[1][r]), fmaxf(sc[2][r], sc[3][r]));
        for (int off = 1; off < 16; off <<= 1)
          cm = fmaxf(cm, __shfl_xor(cm, off, 16));
        float mn = fmaxf(mr[r], cm);
        float corr = __expf(mr[r] - mn);
        mr[r] = mn;
        float ps = 0.0f;
#pragma unroll
        for (int ni = 0; ni < 4; ++ni) {
          float p = __expf(sc[ni][r] - mn);
          Ps[w][quad * 4 + r][ni * 16 + fr] = f2bu(p);
          ps += p;
        }
        for (int off = 1; off < 16; off <<= 1) ps += __shfl_xor(ps, off, 16);
        lr[r] = lr[r] * corr + ps;
#pragma unroll
        for (int dt = 0; dt < 4; ++dt) od[dt][r] *= corr;
      }

      frag8 pf[2];
#pragma unroll
      for (int hh = 0; hh < 2; ++hh)
        pf[hh] = *(const frag8*)&Ps[w][fr][hh * 32 + quad * 8];
#pragma unroll
      for (int dt = 0; dt < 4; ++dt)
#pragma unroll
        for (int hh = 0; hh < 2; ++hh) {
          int vb_ = (((dt * 16 + fr) << 7) + (hh << 6) + (quad << 4)) ^
                    ((fr & 7) << 4);
          frag8 vf = *(const frag8*)(vcur + vb_);
          od[dt] = __builtin_amdgcn_mfma_f32_16x16x32_bf16(pf[hh], vf, od[dt],
                                                           0, 0, 0);
        }
    }
    __syncthreads();
  }

#pragma unroll
  for (int r = 0; r < 4; ++r) {
    float inv = 1.0f / lr[r];
    size_t row = (size_t)(b * SEQ + q0 + w * 16 + quad * 4 + r) * DIMSZ + h * 64;
#pragma unroll
    for (int dt = 0; dt < 4; ++dt)
      ctx[row + dt * 16 + fr] = f2bu(od[dt][r] * inv);
  }
}

// ---------------------------------------------------------------------------
// y = res + pa (+ pb if NP==3); out = scale * y / (||y||*D^-0.5 + eps).
// One block per row. DUAL=1 also writes bf16 copy (GEMM A operand).
// ---------------------------------------------------------------------------
template <int DUAL, int NP>
__global__ __launch_bounds__(256) void add_rmsnorm(
    const float* __restrict__ res, const float* __restrict__ pa,
    const float* __restrict__ pb, const float* __restrict__ scale,
    float* __restrict__ out, ushortt* __restrict__ out2) {
  const int row = blockIdx.x;
  const int tid = threadIdx.x;
  const size_t base = (size_t)row * DIMSZ;
  __shared__ float red[4];
  float y[4];
  float ss = 0.0f;
#pragma unroll
  for (int j = 0; j < 4; ++j) {
    int d = tid + j * 256;
    float yv = res[base + d] + pa[base + d];
    if (NP == 3) yv += pb[base + d];
    y[j] = yv;
    ss += yv * yv;
  }
  for (int off = 1; off < 64; off <<= 1) ss += __shfl_xor(ss, off, 64);
  if ((tid & 63) == 0) red[tid >> 6] = ss;
  __syncthreads();
  float tot = red[0] + red[1] + red[2] + red[3];
  float norm = sqrtf(tot) * 0.03125f;
  float inv = 1.0f / (norm + 1e-8f);
#pragma unroll
  for (int j = 0; j < 4; ++j) {
    int d = tid + j * 256;
    float v = scale[d] * y[j] * inv;
    out[base + d] = v;
    if (DUAL) out2[base + d] = f2bu(v);
  }
}

// ---------------------------------------------------------------------------
extern "C" void kernel_launch(void* const* d_in, const int* in_sizes, int n_in,
                              void* d_out, int out_size, void* d_ws, size_t ws_size,
                              hipStream_t stream) {
  const float* x          = (const float*)d_in[0];
  // d_in[1] = causal mask (bool) — structure hardcoded, unused
  const float* qkv_w      = (const float*)d_in[2];
  const float* attn_out_w = (const float*)d_in[3];
  const float* gate_w     = (const float*)d_in[4];
  const float* gate_b     = (const float*)d_in[5];
  const float* lin_w      = (const float*)d_in[6];
  const float* lin_b      = (const float*)d_in[7];
  const float* ff_out_w   = (const float*)d_in[8];
  const float* n1s        = (const float*)d_in[9];
  const float* n2s        = (const float*)d_in[10];
  float* out = (float*)d_out;

  const int M = NBATCH * SEQ;  // 4096
  char* ws = (char*)d_ws;
  char* dob = (char*)d_out;
  const size_t MB = 1 << 20;
  // ws layout (bytes), lifetime-disjoint; high-water 48 MB:
  ushortt* qkv_tmp = (ushortt*)(ws + 0);        // [0,24)  bf16, p1..rope
  ushortt* xb      = (ushortt*)(ws + 24 * MB);  // [24,32) bf16, p1 (pre-Qr)
  ushortt* qkv_wb  = (ushortt*)(ws + 32 * MB);  // [32,38) bf16, p1 (pre-Kr)
  ushortt* Qr      = (ushortt*)(ws + 24 * MB);  // [24,32) bf16, rope..attn
  ushortt* Kr      = (ushortt*)(ws + 32 * MB);  // [32,40) bf16, rope..attn
  ushortt* Vr      = (ushortt*)(ws + 40 * MB);  // [40,48) bf16, rope..attn
  ushortt* attn_wb = (ushortt*)(ws + 24 * MB);  // [24,26) bf16, p3 (Qr dead)
  float*   proj_a  = (float*)(ws + 0);          // [0,16)  fp32, p3..p4
  float*   proj_b  = (float*)(ws + 40 * MB);    // [40,48) fp32, p3..p4 (Vr dead)
  float*   x1      = (float*)(ws + 16 * MB);    // [16,32) fp32, p4..end
  ushortt* x1b     = (ushortt*)(ws + 32 * MB);  // [32,40) bf16, p4..end
  float*   proj2   = (float*)(ws + 0);          // [0,16)  fp32, p5..end
  ushortt* gcb     = (ushortt*)(ws + 40 * MB);  // [40,44) bf16, p5 chunk (proj_b dead)
  ushortt* lcb     = (ushortt*)(ws + 44 * MB);  // [44,48)
  // d_out doubles as scratch:
  ushortt* ctx  = (ushortt*)(dob + 0);          // [0,8)  bf16, p2..p3
  ushortt* ffc  = (ushortt*)(dob + 0);          // [0,16) bf16, p5 chunk

  // p1: casts + qkv GEMM (bf16 out)
  cast_f2b<<<4194304 / 1024, 256, 0, stream>>>(x, xb, 4194304);
  cast_f2b<<<3145728 / 1024, 256, 0, stream>>>(qkv_w, qkv_wb, 3145728);
  gemm_mfma<1, 1><<<(3072 / 128) * 32, 256, 0, stream>>>(
      xb, qkv_wb, qkv_tmp, M, 3072, DIMSZ, DIMSZ, 0);
  // p2: RoPE prep + MFMA flash attention (balanced 1D grid)
  rope_prep<<<dim3(SEQ / 64, NBATCH * NHEAD), 256, 0, stream>>>(
      qkv_tmp, Qr, Kr, Vr);
  flash_mfma<<<(SEQ / 128) * NBATCH * NHEAD, 512, 0, stream>>>(
      Qr, Kr, Vr, ctx);
  // p3: attn projection, split-K 2 into DISJOINT buffers proj_a/proj_b
  // (512 blocks = 2/CU, no atomics, no zero pass)
  cast_f2b<<<1048576 / 1024, 256, 0, stream>>>(attn_out_w, attn_wb, 1048576);
  gemm_mfma<0, 2><<<(DIMSZ / 128) * 32 * 2, 256, 0, stream>>>(
      ctx, attn_wb, proj_a, M, DIMSZ, DIMSZ, 512,
      (size_t)(40 * MB) / sizeof(float));
  // p4: x1 = rmsnorm(x + proj_a + proj_b), fp32 + bf16 copies
  add_rmsnorm<1, 3><<<M, 256, 0, stream>>>(x, proj_a, proj_b, n1s, x1, x1b);
  // p5: FF in 2 chunks of 2048: pre-cast gate/lin (bf16 keeps B traffic
  // L2-sized), fused gatelin, ffout split-K + atomics into zeroed proj2.
  zero_f32<<<4194304 / 1024, 256, 0, stream>>>(proj2, 4194304);
  for (int c = 0; c < 2; ++c) {
    cast_f2b<<<2048, 256, 0, stream>>>(
        gate_w + (size_t)c * 2097152, gcb, 2097152);
    cast_f2b<<<2048, 256, 0, stream>>>(
        lin_w + (size_t)c * 2097152, lcb, 2097152);
    gemm_gatelin<<<(2048 / 128) * 32, 256, 0, stream>>>(
        x1b, gcb, lcb, ffc, gate_b + c * 2048, lin_b + c * 2048,
        M, 2048, DIMSZ);
    gemm_ffout<<<(1024 / 128) * 32 * 2, 256, 0, stream>>>(
        ffc, ff_out_w, proj2, c * 2048);
  }
  // p6: out = rmsnorm(x1 + proj2)
  add_rmsnorm<0, 2><<<M, 256, 0, stream>>>(x1, proj2, nullptr, n2s, out,
                                           nullptr);
}

// Round 9
// 557.963 us; speedup vs baseline: 1.1820x; 1.0106x over previous
//
#include <hip/hip_runtime.h>
#include <hip/hip_bf16.h>
#include <math.h>

#define DIMSZ 1024
#define NHEAD 16
#define HDIM 64
#define FFDIM 4096
#define SEQ 2048
#define NBATCH 2

typedef unsigned short ushortt;
typedef __attribute__((ext_vector_type(8))) short frag8;   // 8 bf16 (4 VGPR)
typedef __attribute__((ext_vector_type(4))) float f32x4;   // MFMA acc

// bf16 (stored as ushort) <-> fp32
__device__ __forceinline__ float u2f(ushortt u) {
  return __uint_as_float(((unsigned)u) << 16);
}
__device__ __forceinline__ ushortt f2bu(float f) {  // RNE
  unsigned x = __float_as_uint(f);
  return (ushortt)((x + 0x7FFFu + ((x >> 16) & 1u)) >> 16);
}

// ---------------------------------------------------------------------------
// fp32 -> bf16 cast, 4 elems/thread, n % 4 == 0
// ---------------------------------------------------------------------------
__global__ __launch_bounds__(256) void cast_f2b(
    const float* __restrict__ src, ushortt* __restrict__ dst, int n) {
  int i = (blockIdx.x * 256 + threadIdx.x) * 4;
  if (i >= n) return;
  float4 f = *(const float4*)(src + i);
  ushort4 u;
  u.x = f2bu(f.x); u.y = f2bu(f.y); u.z = f2bu(f.z); u.w = f2bu(f.w);
  *(ushort4*)(dst + i) = u;
}

// ---------------------------------------------------------------------------
// zero fp32 buffer (pre-pass for atomic-accumulate GEMMs), n % 4 == 0
// ---------------------------------------------------------------------------
__global__ __launch_bounds__(256) void zero_f32(float* __restrict__ p, int n) {
  int i = (blockIdx.x * 256 + threadIdx.x) * 4;
  if (i < n) *(float4*)(p + i) = make_float4(0.f, 0.f, 0.f, 0.f);
}

// ---------------------------------------------------------------------------
// MFMA GEMM, double-buffered with COUNTED-vmcnt raw barriers (AITER T4):
// stage(t+1) stays in flight across the barrier; each wave waits only for
// its own tile-t loads (vmcnt(4) = 4 younger loads outstanding). vmcnt(0)
// only on the last iteration. sched_barrier(0) fences stop the compiler
// hoisting LDS frag reads above the wait (rule #18).
// 1D grid, XCD-grouped decode. SK=2: split-K, kz=1 writes C + skoff.
// EPI: 0 fp32 store | 1 bf16 store
// ---------------------------------------------------------------------------
template <int EPI, int SK>
__global__ __launch_bounds__(256) void gemm_mfma(
    const ushortt* __restrict__ A, const ushortt* __restrict__ W,
    void* __restrict__ Cv, int M, int N, int K, int KB, size_t skoff) {
  __shared__ __align__(16) short As[2][128 * 32];
  __shared__ __align__(16) short Bs[2][128 * 32];
  const int tid = threadIdx.x;
  const int wave = tid >> 6;
  const int lane = tid & 63;
  int xcd = blockIdx.x & 7, r = blockIdx.x >> 3, kz = 0;
  if (SK == 2) { kz = r & 1; r >>= 1; }
  const int bm = (xcd * 4 + (r & 3)) * 128;
  const int bn = (r >> 2) * 128;
  const int ko0 = kz * KB;
  const int wm = (wave >> 1) * 64;
  const int wn = (wave & 1) * 64;

  f32x4 acc[4][4] = {};

  const int sr = lane >> 2;
  const int sc = (lane & 3) * 8;
  const ushortt* pa0 = A + (size_t)(bm + wave * 16 + sr) * K + ko0 + sc;
  const ushortt* pa1 = pa0 + (size_t)64 * K;
  const ushortt* pb0 = W + (size_t)(bn + wave * 16 + sr) * K + ko0 + sc;
  const ushortt* pb1 = pb0 + (size_t)64 * K;
  const int lo0 = (wave * 16) * 32;
  const int lo1 = (64 + wave * 16) * 32;

  const int fr = lane & 15;
  const int fq = (lane >> 4) * 8;
  const int nt = KB >> 5;

  auto stage = [&](int t, int buf) {
    const int ko = t * 32;
    short* ab = &As[0][0] + buf * 4096;
    short* bb = &Bs[0][0] + buf * 4096;
    __builtin_amdgcn_global_load_lds(
        (const __attribute__((address_space(1))) void*)(pa0 + ko),
        (__attribute__((address_space(3))) void*)(ab + lo0), 16, 0, 0);
    __builtin_amdgcn_global_load_lds(
        (const __attribute__((address_space(1))) void*)(pa1 + ko),
        (__attribute__((address_space(3))) void*)(ab + lo1), 16, 0, 0);
    __builtin_amdgcn_global_load_lds(
        (const __attribute__((address_space(1))) void*)(pb0 + ko),
        (__attribute__((address_space(3))) void*)(bb + lo0), 16, 0, 0);
    __builtin_amdgcn_global_load_lds(
        (const __attribute__((address_space(1))) void*)(pb1 + ko),
        (__attribute__((address_space(3))) void*)(bb + lo1), 16, 0, 0);
  };

  stage(0, 0);

  for (int t = 0; t < nt; ++t) {
    if (t + 1 < nt) {
      stage(t + 1, (t + 1) & 1);
      asm volatile("s_waitcnt vmcnt(4)" ::: "memory");  // tile-t loads done
    } else {
      asm volatile("s_waitcnt vmcnt(0)" ::: "memory");
    }
    __builtin_amdgcn_s_barrier();
    __builtin_amdgcn_sched_barrier(0);
    const short* as = &As[0][0] + (t & 1) * 4096;
    const short* bs = &Bs[0][0] + (t & 1) * 4096;

    frag8 af[4], bf[4];
#pragma unroll
    for (int mi = 0; mi < 4; ++mi)
      af[mi] = *(const frag8*)&as[(wm + mi * 16 + fr) * 32 + fq];
#pragma unroll
    for (int ni = 0; ni < 4; ++ni)
      bf[ni] = *(const frag8*)&bs[(wn + ni * 16 + fr) * 32 + fq];
#pragma unroll
    for (int mi = 0; mi < 4; ++mi)
#pragma unroll
      for (int ni = 0; ni < 4; ++ni)
        acc[mi][ni] = __builtin_amdgcn_mfma_f32_16x16x32_bf16(
            af[mi], bf[ni], acc[mi][ni], 0, 0, 0);
    __builtin_amdgcn_sched_barrier(0);
    __builtin_amdgcn_s_barrier();  // all waves done reading buf[t&1]
  }

  const int er = (lane >> 4) * 4;
  const int ec = lane & 15;
  float* C0 = (float*)Cv + (SK == 2 ? (size_t)kz * skoff : 0);
#pragma unroll
  for (int mi = 0; mi < 4; ++mi)
#pragma unroll
    for (int ni = 0; ni < 4; ++ni)
#pragma unroll
      for (int r2 = 0; r2 < 4; ++r2) {
        int m = bm + wm + mi * 16 + er + r2;
        int n = bn + wn + ni * 16 + ec;
        size_t o = (size_t)m * N + n;
        float v = acc[mi][ni][r2];
        if (EPI == 0) {
          C0[o] = v;
        } else {
          ((ushortt*)Cv)[o] = f2bu(v);
        }
      }
}

// ---------------------------------------------------------------------------
// Fused gate+lin GEMM: one staged A tile + TWO pre-cast bf16 B tiles via
// global_load_lds; 32 MFMA/K-step. Counted-vmcnt raw barriers (6 loads in
// flight). Epilogue: out = sigmoid(g+gbias)*(l+lbias) -> bf16.
// ---------------------------------------------------------------------------
__global__ __launch_bounds__(256) void gemm_gatelin(
    const ushortt* __restrict__ A, const ushortt* __restrict__ Wg,
    const ushortt* __restrict__ Wl, ushortt* __restrict__ Cv,
    const float* __restrict__ gbias, const float* __restrict__ lbias,
    int M, int N, int K) {
  __shared__ __align__(16) short As[2][128 * 32];
  __shared__ __align__(16) short Gs[2][128 * 32];
  __shared__ __align__(16) short Ls[2][128 * 32];
  const int tid = threadIdx.x;
  const int wave = tid >> 6;
  const int lane = tid & 63;
  int xcd = blockIdx.x & 7, r = blockIdx.x >> 3;
  const int bm = (xcd * 4 + (r & 3)) * 128;
  const int bn = (r >> 2) * 128;
  const int wm = (wave >> 1) * 64;
  const int wn = (wave & 1) * 64;

  f32x4 accg[4][4] = {};
  f32x4 accl[4][4] = {};

  const int sr = lane >> 2;
  const int sc = (lane & 3) * 8;
  const ushortt* pa0 = A + (size_t)(bm + wave * 16 + sr) * K + sc;
  const ushortt* pa1 = pa0 + (size_t)64 * K;
  const ushortt* pg0 = Wg + (size_t)(bn + wave * 16 + sr) * K + sc;
  const ushortt* pg1 = pg0 + (size_t)64 * K;
  const ushortt* pl0 = Wl + (size_t)(bn + wave * 16 + sr) * K + sc;
  const ushortt* pl1 = pl0 + (size_t)64 * K;
  const int lo0 = (wave * 16) * 32;
  const int lo1 = (64 + wave * 16) * 32;

  const int fr = lane & 15;
  const int fq = (lane >> 4) * 8;
  const int nt = K >> 5;

  auto stage = [&](int t, int buf) {
    const int ko = t * 32;
    short* ab = &As[0][0] + buf * 4096;
    short* gb = &Gs[0][0] + buf * 4096;
    short* lb = &Ls[0][0] + buf * 4096;
    __builtin_amdgcn_global_load_lds(
        (const __attribute__((address_space(1))) void*)(pa0 + ko),
        (__attribute__((address_space(3))) void*)(ab + lo0), 16, 0, 0);
    __builtin_amdgcn_global_load_lds(
        (const __attribute__((address_space(1))) void*)(pa1 + ko),
        (__attribute__((address_space(3))) void*)(ab + lo1), 16, 0, 0);
    __builtin_amdgcn_global_load_lds(
        (const __attribute__((address_space(1))) void*)(pg0 + ko),
        (__attribute__((address_space(3))) void*)(gb + lo0), 16, 0, 0);
    __builtin_amdgcn_global_load_lds(
        (const __attribute__((address_space(1))) void*)(pg1 + ko),
        (__attribute__((address_space(3))) void*)(gb + lo1), 16, 0, 0);
    __builtin_amdgcn_global_load_lds(
        (const __attribute__((address_space(1))) void*)(pl0 + ko),
        (__attribute__((address_space(3))) void*)(lb + lo0), 16, 0, 0);
    __builtin_amdgcn_global_load_lds(
        (const __attribute__((address_space(1))) void*)(pl1 + ko),
        (__attribute__((address_space(3))) void*)(lb + lo1), 16, 0, 0);
  };

  stage(0, 0);

  for (int t = 0; t < nt; ++t) {
    if (t + 1 < nt) {
      stage(t + 1, (t + 1) & 1);
      asm volatile("s_waitcnt vmcnt(6)" ::: "memory");
    } else {
      asm volatile("s_waitcnt vmcnt(0)" ::: "memory");
    }
    __builtin_amdgcn_s_barrier();
    __builtin_amdgcn_sched_barrier(0);
    const short* as = &As[0][0] + (t & 1) * 4096;
    const short* gs = &Gs[0][0] + (t & 1) * 4096;
    const short* ls = &Ls[0][0] + (t & 1) * 4096;

    frag8 af[4], gf[4], lf[4];
#pragma unroll
    for (int mi = 0; mi < 4; ++mi)
      af[mi] = *(const frag8*)&as[(wm + mi * 16 + fr) * 32 + fq];
#pragma unroll
    for (int ni = 0; ni < 4; ++ni) {
      gf[ni] = *(const frag8*)&gs[(wn + ni * 16 + fr) * 32 + fq];
      lf[ni] = *(const frag8*)&ls[(wn + ni * 16 + fr) * 32 + fq];
    }
#pragma unroll
    for (int mi = 0; mi < 4; ++mi)
#pragma unroll
      for (int ni = 0; ni < 4; ++ni) {
        accg[mi][ni] = __builtin_amdgcn_mfma_f32_16x16x32_bf16(
            af[mi], gf[ni], accg[mi][ni], 0, 0, 0);
        accl[mi][ni] = __builtin_amdgcn_mfma_f32_16x16x32_bf16(
            af[mi], lf[ni], accl[mi][ni], 0, 0, 0);
      }
    __builtin_amdgcn_sched_barrier(0);
    __builtin_amdgcn_s_barrier();
  }

  const int er = (lane >> 4) * 4;
  const int ec = lane & 15;
#pragma unroll
  for (int mi = 0; mi < 4; ++mi)
#pragma unroll
    for (int ni = 0; ni < 4; ++ni)
#pragma unroll
      for (int r2 = 0; r2 < 4; ++r2) {
        int m = bm + wm + mi * 16 + er + r2;
        int n = bn + wn + ni * 16 + ec;
        size_t o = (size_t)m * N + n;
        float g = accg[mi][ni][r2] + gbias[n];
        float l = accl[mi][ni][r2] + lbias[n];
        float sig = 1.0f / (1.0f + __expf(-g));
        ((ushortt*)Cv)[o] = f2bu(sig * l);
      }
}

// ---------------------------------------------------------------------------
// FF-out GEMM, split-K + on-the-fly fp32->bf16 B staging, counted vmcnt.
// bload issued BEFORE astage so the compiler's f-reg wait (vmcnt(2)) leaves
// the A prefetch in flight; explicit vmcnt(6) covers tile-t's astage.
// lgkmcnt(0) before end barrier makes the cross-wave ds_writes visible.
// Atomic fp32 accumulate into zero-initialized C.
// ---------------------------------------------------------------------------
__global__ __launch_bounds__(256) void gemm_ffout(
    const ushortt* __restrict__ A, const float* __restrict__ Bw,
    float* __restrict__ C, int koff) {
  __shared__ __align__(16) short As[2][128 * 32];
  __shared__ __align__(16) short Bs[2][128 * 32];
  const int tid = threadIdx.x;
  const int wave = tid >> 6;
  const int lane = tid & 63;
  int xcd = blockIdx.x & 7, r = blockIdx.x >> 3;
  const int kz = r & 1; r >>= 1;
  const int bm = (xcd * 4 + (r & 3)) * 128;
  const int bn = (r >> 2) * 128;
  const int wm = (wave >> 1) * 64;
  const int wn = (wave & 1) * 64;

  f32x4 acc[4][4] = {};

  const int sr = lane >> 2;
  const int sc = (lane & 3) * 8;
  const ushortt* pa0 = A + (size_t)(bm + wave * 16 + sr) * 2048 + kz * 1024 + sc;
  const ushortt* pa1 = pa0 + (size_t)64 * 2048;
  const int lo0 = (wave * 16) * 32;
  const int lo1 = (64 + wave * 16) * 32;

  const int br = tid >> 2;
  const int kc = (tid & 3) * 8;
  const float* pb0 = Bw + (size_t)(bn + br) * FFDIM + koff + kz * 1024 + kc;
  const float* pb1 = pb0 + (size_t)64 * FFDIM;

  const int fr = lane & 15;
  const int fq = (lane >> 4) * 8;
  const int nt = 1024 >> 5;  // 32

  float4 f0, f1, f2, f3;
  auto bload = [&](int t) {
    const float* p0 = pb0 + t * 32;
    const float* p1 = pb1 + t * 32;
    f0 = *(const float4*)p0; f1 = *(const float4*)(p0 + 4);
    f2 = *(const float4*)p1; f3 = *(const float4*)(p1 + 4);
  };
  auto pk = [&](float4 a, float4 b) {
    frag8 v;
    v[0] = (short)f2bu(a.x); v[1] = (short)f2bu(a.y);
    v[2] = (short)f2bu(a.z); v[3] = (short)f2bu(a.w);
    v[4] = (short)f2bu(b.x); v[5] = (short)f2bu(b.y);
    v[6] = (short)f2bu(b.z); v[7] = (short)f2bu(b.w);
    return v;
  };
  auto bwrite = [&](int buf) {
    *(frag8*)&Bs[buf][tid * 8] = pk(f0, f1);
    *(frag8*)&Bs[buf][2048 + tid * 8] = pk(f2, f3);
  };
  auto astage = [&](int t, int buf) {
    const int ko = t * 32;
    short* ab = &As[0][0] + buf * 4096;
    __builtin_amdgcn_global_load_lds(
        (const __attribute__((address_space(1))) void*)(pa0 + ko),
        (__attribute__((address_space(3))) void*)(ab + lo0), 16, 0, 0);
    __builtin_amdgcn_global_load_lds(
        (const __attribute__((address_space(1))) void*)(pa1 + ko),
        (__attribute__((address_space(3))) void*)(ab + lo1), 16, 0, 0);
  };

  // prologue: bload first (older) so bwrite's implicit wait leaves astage
  // in flight; drain ds_writes for cross-wave visibility.
  bload(0);
  astage(0, 0);
  bwrite(0);
  asm volatile("s_waitcnt lgkmcnt(0)" ::: "memory");

  for (int t = 0; t < nt; ++t) {
    if (t + 1 < nt) {
      bload(t + 1);
      astage(t + 1, (t + 1) & 1);
      asm volatile("s_waitcnt vmcnt(6)" ::: "memory");  // astage(t) done
    } else {
      asm volatile("s_waitcnt vmcnt(0)" ::: "memory");
    }
    __builtin_amdgcn_s_barrier();
    __builtin_amdgcn_sched_barrier(0);
    const short* as = &As[0][0] + (t & 1) * 4096;
    const short* bs = &Bs[0][0] + (t & 1) * 4096;

    frag8 af[4], bf[4];
#pragma unroll
    for (int mi = 0; mi < 4; ++mi)
      af[mi] = *(const frag8*)&as[(wm + mi * 16 + fr) * 32 + fq];
#pragma unroll
    for (int ni = 0; ni < 4; ++ni)
      bf[ni] = *(const frag8*)&bs[(wn + ni * 16 + fr) * 32 + fq];
#pragma unroll
    for (int mi = 0; mi < 4; ++mi)
#pragma unroll
      for (int ni = 0; ni < 4; ++ni)
        acc[mi][ni] = __builtin_amdgcn_mfma_f32_16x16x32_bf16(
            af[mi], bf[ni], acc[mi][ni], 0, 0, 0);
    if (t + 1 < nt) bwrite((t + 1) & 1);  // implicit vmcnt(2) for f-regs
    asm volatile("s_waitcnt lgkmcnt(0)" ::: "memory");
    __builtin_amdgcn_sched_barrier(0);
    __builtin_amdgcn_s_barrier();
  }

  const int er = (lane >> 4) * 4;
  const int ec = lane & 15;
#pragma unroll
  for (int mi = 0; mi < 4; ++mi)
#pragma unroll
    for (int ni = 0; ni < 4; ++ni)
#pragma unroll
      for (int r2 = 0; r2 < 4; ++r2) {
        int m = bm + wm + mi * 16 + er + r2;
        int n = bn + wn + ni * 16 + ec;
        unsafeAtomicAdd(C + (size_t)m * 1024 + n, acc[mi][ni][r2]);
      }
}

// ---------------------------------------------------------------------------
// RoPE prep: qkv (B,S,3,H,D) bf16 -> Qr,Kr [bh][S][64] (Q scaled 1/8),
// Vr chunk-blocked [bh][S/64][64 d][64 key] (transposed per 64-seq chunk).
// ---------------------------------------------------------------------------
__global__ __launch_bounds__(256) void rope_prep(
    const ushortt* __restrict__ qkv, ushortt* __restrict__ Qr,
    ushortt* __restrict__ Kr, ushortt* __restrict__ Vr) {
  const int s0 = blockIdx.x * 64;
  const int bh = blockIdx.y;
  const int b = bh >> 4, h = bh & 15;
  const int tid = threadIdx.x;
  __shared__ float ifr_s[32];
  __shared__ ushortt vt[64][72];
  if (tid < 32) ifr_s[tid] = __powf(10000.0f, -(float)tid * (1.0f / 32.0f));
  __syncthreads();
  const size_t qbase = (size_t)bh * SEQ * 64;

#pragma unroll
  for (int i = 0; i < 8; ++i) {
    int p = i * 256 + tid;
    int r = p >> 5, d = p & 31;
    size_t src = ((size_t)(b * SEQ + s0 + r)) * (3 * DIMSZ) + h * 64 + d;
    float q1 = u2f(qkv[src]), q2 = u2f(qkv[src + 32]);
    float k1 = u2f(qkv[src + DIMSZ]), k2 = u2f(qkv[src + DIMSZ + 32]);
    float ang = (float)(s0 + r) * ifr_s[d];
    float sn, cs;
    __sincosf(ang, &sn, &cs);
    size_t dst = qbase + (size_t)(s0 + r) * 64 + d;
    Qr[dst]      = f2bu((q1 * cs - q2 * sn) * 0.125f);
    Qr[dst + 32] = f2bu((q1 * sn + q2 * cs) * 0.125f);
    Kr[dst]      = f2bu(k1 * cs - k2 * sn);
    Kr[dst + 32] = f2bu(k1 * sn + k2 * cs);
  }

#pragma unroll
  for (int i = 0; i < 2; ++i) {
    int e = (i * 256 + tid) * 8;
    int r = e >> 6, d0 = e & 63;
    size_t src = ((size_t)(b * SEQ + s0 + r)) * (3 * DIMSZ) + 2 * DIMSZ + h * 64 + d0;
    *(ushort4*)&vt[r][d0]     = *(const ushort4*)(qkv + src);
    *(ushort4*)&vt[r][d0 + 4] = *(const ushort4*)(qkv + src + 4);
  }
  __syncthreads();
  {
    int d = tid >> 2;
    int sc0 = (tid & 3) * 16;
    size_t dst = (size_t)bh * 64 * SEQ + (size_t)blockIdx.x * 4096 +
                 (size_t)d * 64 + sc0;
    ushortt tmp[16];
#pragma unroll
    for (int j = 0; j < 16; ++j) tmp[j] = vt[sc0 + j][d];
    *(ushort4*)(Vr + dst)      = *(ushort4*)&tmp[0];
    *(ushort4*)(Vr + dst + 4)  = *(ushort4*)&tmp[4];
    *(ushort4*)(Vr + dst + 8)  = *(ushort4*)&tmp[8];
    *(ushort4*)(Vr + dst + 12) = *(ushort4*)&tmp[12];
  }
}

// ---------------------------------------------------------------------------
// MFMA flash attention, LDS-staged K/V, counted-vmcnt raw barriers
// (stage = 2 loads -> vmcnt(2)). Balanced 1D grid (qt paired with 15-qt).
// XOR-swizzle byte^=((row&7)<<4) on both sides (rule #21).
// ---------------------------------------------------------------------------
__global__ __launch_bounds__(512) void flash_mfma(
    const ushortt* __restrict__ Qr, const ushortt* __restrict__ Kr,
    const ushortt* __restrict__ Vr, ushortt* __restrict__ ctx) {
  const int id = blockIdx.x;
  const int r5 = id & 255;
  const int qt0 = r5 >> 5;
  const int qt = (id & 256) ? (15 - qt0) : qt0;   // balanced pairing
  const int bh = r5 & 31;
  const int q0 = qt * 128;
  const int b = bh >> 4, h = bh & 15;
  const int tid = threadIdx.x;
  const int w = tid >> 6;
  const int lane = tid & 63;
  const int fr = lane & 15;
  const int quad = lane >> 4;

  __shared__ __align__(16) short Kb[2][4096];
  __shared__ __align__(16) short Vb[2][4096];
  __shared__ __align__(16) ushortt Ps[8][16][72];

  const size_t qkbase = (size_t)bh * SEQ * 64;
  const size_t vbase = (size_t)bh * 64 * SEQ;

  const int lin = (w << 10) + ((lane & 63) << 4);
  const int swz = lin ^ (((lin >> 7) & 7) << 4);
  const char* ksrc = (const char*)(Kr + qkbase) + swz;
  const char* vsrc = (const char*)(Vr + vbase) + swz;
  short* kdst[2] = {&Kb[0][w * 512], &Kb[1][w * 512]};
  short* vdst[2] = {&Vb[0][w * 512], &Vb[1][w * 512]};

  frag8 aq[2];
#pragma unroll
  for (int hh = 0; hh < 2; ++hh)
    aq[hh] = *(const frag8*)(Qr + qkbase + (size_t)(q0 + w * 16 + fr) * 64 +
                             hh * 32 + quad * 8);

  float mr[4], lr[4];
  f32x4 od[4] = {};
#pragma unroll
  for (int r = 0; r < 4; ++r) { mr[r] = -1e30f; lr[r] = 0.0f; }

  const int nt = 2 * qt + 2;

  __builtin_amdgcn_global_load_lds(
      (const __attribute__((address_space(1))) void*)ksrc,
      (__attribute__((address_space(3))) void*)kdst[0], 16, 0, 0);
  __builtin_amdgcn_global_load_lds(
      (const __attribute__((address_space(1))) void*)vsrc,
      (__attribute__((address_space(3))) void*)vdst[0], 16, 0, 0);

  for (int t = 0; t < nt; ++t) {
    const int c0 = t * 64;
    if (t + 1 < nt) {
      const char* kn = ksrc + (size_t)(t + 1) * 8192;
      const char* vn = vsrc + (size_t)(t + 1) * 8192;
      __builtin_amdgcn_global_load_lds(
          (const __attribute__((address_space(1))) void*)kn,
          (__attribute__((address_space(3))) void*)kdst[(t + 1) & 1], 16, 0, 0);
      __builtin_amdgcn_global_load_lds(
          (const __attribute__((address_space(1))) void*)vn,
          (__attribute__((address_space(3))) void*)vdst[(t + 1) & 1], 16, 0, 0);
      asm volatile("s_waitcnt vmcnt(2)" ::: "memory");
    } else {
      asm volatile("s_waitcnt vmcnt(0)" ::: "memory");
    }
    __builtin_amdgcn_s_barrier();
    __builtin_amdgcn_sched_barrier(0);
    const char* kcur = (const char*)Kb[t & 1];
    const char* vcur = (const char*)Vb[t & 1];

    if (c0 <= q0 + w * 16 + 15) {
      f32x4 sc[4] = {};
#pragma unroll
      for (int ni = 0; ni < 4; ++ni)
#pragma unroll
        for (int hh = 0; hh < 2; ++hh) {
          int kb = (((ni * 16 + fr) << 7) + (hh << 6) + (quad << 4)) ^
                   ((fr & 7) << 4);
          frag8 kf = *(const frag8*)(kcur + kb);
          sc[ni] = __builtin_amdgcn_mfma_f32_16x16x32_bf16(aq[hh], kf, sc[ni],
                                                           0, 0, 0);
        }

      if (c0 + 63 > q0 + w * 16) {
        int rowb = q0 + w * 16 + quad * 4;
#pragma unroll
        for (int ni = 0; ni < 4; ++ni) {
          int col = c0 + ni * 16 + fr;
#pragma unroll
          for (int r = 0; r < 4; ++r)
            if (col > rowb + r) sc[ni][r] = -1e30f;
        }
      }

#pragma unroll
      for (int r = 0; r < 4; ++r) {
        float cm = fmaxf(fmaxf(sc[0][r], sc[1][r]), fmaxf(sc[2][r], sc[3][r]));
        for (int off = 1; off < 16; off <<= 1)
          cm = fmaxf(cm, __shfl_xor(cm, off, 16));
        float mn = fmaxf(mr[r], cm);
        float corr = __expf(mr[r] - mn);
        mr[r] = mn;
        float ps = 0.0f;
#pragma unroll
        for (int ni = 0; ni < 4; ++ni) {
          float p = __expf(sc[ni][r] - mn);
          Ps[w][quad * 4 + r][ni * 16 + fr] = f2bu(p);
          ps += p;
        }
        for (int off = 1; off < 16; off <<= 1) ps += __shfl_xor(ps, off, 16);
        lr[r] = lr[r] * corr + ps;
#pragma unroll
        for (int dt = 0; dt < 4; ++dt) od[dt][r] *= corr;
      }

      frag8 pf[2];
#pragma unroll
      for (int hh = 0; hh < 2; ++hh)
        pf[hh] = *(const frag8*)&Ps[w][fr][hh * 32 + quad * 8];
#pragma unroll
      for (int dt = 0; dt < 4; ++dt)
#pragma unroll
        for (int hh = 0; hh < 2; ++hh) {
          int vb_ = (((dt * 16 + fr) << 7) + (hh << 6) + (quad << 4)) ^
                    ((fr & 7) << 4);
          frag8 vf = *(const frag8*)(vcur + vb_);
          od[dt] = __builtin_amdgcn_mfma_f32_16x16x32_bf16(pf[hh], vf, od[dt],
                                                           0, 0, 0);
        }
    }
    __builtin_amdgcn_sched_barrier(0);
    __builtin_amdgcn_s_barrier();
  }

#pragma unroll
  for (int r = 0; r < 4; ++r) {
    float inv = 1.0f / lr[r];
    size_t row = (size_t)(b * SEQ + q0 + w * 16 + quad * 4 + r) * DIMSZ + h * 64;
#pragma unroll
    for (int dt = 0; dt < 4; ++dt)
      ctx[row + dt * 16 + fr] = f2bu(od[dt][r] * inv);
  }
}

// ---------------------------------------------------------------------------
// y = res + pa (+ pb if NP==3); out = scale * y / (||y||*D^-0.5 + eps).
// One block per row. DUAL=1 also writes bf16 copy (GEMM A operand).
// ---------------------------------------------------------------------------
template <int DUAL, int NP>
__global__ __launch_bounds__(256) void add_rmsnorm(
    const float* __restrict__ res, const float* __restrict__ pa,
    const float* __restrict__ pb, const float* __restrict__ scale,
    float* __restrict__ out, ushortt* __restrict__ out2) {
  const int row = blockIdx.x;
  const int tid = threadIdx.x;
  const size_t base = (size_t)row * DIMSZ;
  __shared__ float red[4];
  float y[4];
  float ss = 0.0f;
#pragma unroll
  for (int j = 0; j < 4; ++j) {
    int d = tid + j * 256;
    float yv = res[base + d] + pa[base + d];
    if (NP == 3) yv += pb[base + d];
    y[j] = yv;
    ss += yv * yv;
  }
  for (int off = 1; off < 64; off <<= 1) ss += __shfl_xor(ss, off, 64);
  if ((tid & 63) == 0) red[tid >> 6] = ss;
  __syncthreads();
  float tot = red[0] + red[1] + red[2] + red[3];
  float norm = sqrtf(tot) * 0.03125f;
  float inv = 1.0f / (norm + 1e-8f);
#pragma unroll
  for (int j = 0; j < 4; ++j) {
    int d = tid + j * 256;
    float v = scale[d] * y[j] * inv;
    out[base + d] = v;
    if (DUAL) out2[base + d] = f2bu(v);
  }
}

// ---------------------------------------------------------------------------
extern "C" void kernel_launch(void* const* d_in, const int* in_sizes, int n_in,
                              void* d_out, int out_size, void* d_ws, size_t ws_size,
                              hipStream_t stream) {
  const float* x          = (const float*)d_in[0];
  // d_in[1] = causal mask (bool) — structure hardcoded, unused
  const float* qkv_w      = (const float*)d_in[2];
  const float* attn_out_w = (const float*)d_in[3];
  const float* gate_w     = (const float*)d_in[4];
  const float* gate_b     = (const float*)d_in[5];
  const float* lin_w      = (const float*)d_in[6];
  const float* lin_b      = (const float*)d_in[7];
  const float* ff_out_w   = (const float*)d_in[8];
  const float* n1s        = (const float*)d_in[9];
  const float* n2s        = (const float*)d_in[10];
  float* out = (float*)d_out;

  const int M = NBATCH * SEQ;  // 4096
  char* ws = (char*)d_ws;
  char* dob = (char*)d_out;
  const size_t MB = 1 << 20;
  // ws layout (bytes), lifetime-disjoint; high-water 48 MB:
  ushortt* qkv_tmp = (ushortt*)(ws + 0);        // [0,24)  bf16, p1..rope
  ushortt* xb      = (ushortt*)(ws + 24 * MB);  // [24,32) bf16, p1 (pre-Qr)
  ushortt* qkv_wb  = (ushortt*)(ws + 32 * MB);  // [32,38) bf16, p1 (pre-Kr)
  ushortt* Qr      = (ushortt*)(ws + 24 * MB);  // [24,32) bf16, rope..attn
  ushortt* Kr      = (ushortt*)(ws + 32 * MB);  // [32,40) bf16, rope..attn
  ushortt* Vr      = (ushortt*)(ws + 40 * MB);  // [40,48) bf16, rope..attn
  ushortt* attn_wb = (ushortt*)(ws + 24 * MB);  // [24,26) bf16, p3 (Qr dead)
  float*   proj_a  = (float*)(ws + 0);          // [0,16)  fp32, p3..p4
  float*   proj_b  = (float*)(ws + 40 * MB);    // [40,48) fp32, p3..p4 (Vr dead)
  float*   x1      = (float*)(ws + 16 * MB);    // [16,32) fp32, p4..end
  ushortt* x1b     = (ushortt*)(ws + 32 * MB);  // [32,40) bf16, p4..end
  float*   proj2   = (float*)(ws + 0);          // [0,16)  fp32, p5..end
  ushortt* gcb     = (ushortt*)(ws + 40 * MB);  // [40,44) bf16, p5 chunk (proj_b dead)
  ushortt* lcb     = (ushortt*)(ws + 44 * MB);  // [44,48)
  // d_out doubles as scratch:
  ushortt* ctx  = (ushortt*)(dob + 0);          // [0,8)  bf16, p2..p3
  ushortt* ffc  = (ushortt*)(dob + 0);          // [0,16) bf16, p5 chunk

  // p1: casts + qkv GEMM (bf16 out)
  cast_f2b<<<4194304 / 1024, 256, 0, stream>>>(x, xb, 4194304);
  cast_f2b<<<3145728 / 1024, 256, 0, stream>>>(qkv_w, qkv_wb, 3145728);
  gemm_mfma<1, 1><<<(3072 / 128) * 32, 256, 0, stream>>>(
      xb, qkv_wb, qkv_tmp, M, 3072, DIMSZ, DIMSZ, 0);
  // p2: RoPE prep + MFMA flash attention (balanced 1D grid)
  rope_prep<<<dim3(SEQ / 64, NBATCH * NHEAD), 256, 0, stream>>>(
      qkv_tmp, Qr, Kr, Vr);
  flash_mfma<<<(SEQ / 128) * NBATCH * NHEAD, 512, 0, stream>>>(
      Qr, Kr, Vr, ctx);
  // p3: attn projection, split-K 2 into DISJOINT buffers proj_a/proj_b
  cast_f2b<<<1048576 / 1024, 256, 0, stream>>>(attn_out_w, attn_wb, 1048576);
  gemm_mfma<0, 2><<<(DIMSZ / 128) * 32 * 2, 256, 0, stream>>>(
      ctx, attn_wb, proj_a, M, DIMSZ, DIMSZ, 512,
      (size_t)(40 * MB) / sizeof(float));
  // p4: x1 = rmsnorm(x + proj_a + proj_b), fp32 + bf16 copies
  add_rmsnorm<1, 3><<<M, 256, 0, stream>>>(x, proj_a, proj_b, n1s, x1, x1b);
  // p5: FF in 2 chunks of 2048: pre-cast gate/lin, fused gatelin, ffout
  // split-K + atomics into zeroed proj2.
  zero_f32<<<4194304 / 1024, 256, 0, stream>>>(proj2, 4194304);
  for (int c = 0; c < 2; ++c) {
    cast_f2b<<<2048, 256, 0, stream>>>(
        gate_w + (size_t)c * 2097152, gcb, 2097152);
    cast_f2b<<<2048, 256, 0, stream>>>(
        lin_w + (size_t)c * 2097152, lcb, 2097152);
    gemm_gatelin<<<(2048 / 128) * 32, 256, 0, stream>>>(
        x1b, gcb, lcb, ffc, gate_b + c * 2048, lin_b + c * 2048,
        M, 2048, DIMSZ);
    gemm_ffout<<<(1024 / 128) * 32 * 2, 256, 0, stream>>>(
        ffc, ff_out_w, proj2, c * 2048);
  }
  // p6: out = rmsnorm(x1 + proj2)
  add_rmsnorm<0, 2><<<M, 256, 0, stream>>>(x1, proj2, nullptr, n2s, out,
                                           nullptr);
}